// Round 1
// baseline (3898.293 us; speedup 1.0000x reference)
//
#include <hip/hip_runtime.h>
#include <cstddef>

#define DD 300
#define HH 600
#define LL 5
#define NGG 512

// ---------------- Atom encoder: h[n,d] = sum_f atom_emb[x[n,f]+64f][d] ----------------
__global__ __launch_bounds__(320) void atom_kernel(const int* __restrict__ x,
    const float* __restrict__ emb, float* __restrict__ h, int N)
{
    __shared__ int xi[9];
    int n = blockIdx.x;
    int t = threadIdx.x;
    if (t < 9) xi[t] = x[n * 9 + t] + t * 64;
    __syncthreads();
    if (t >= DD) return;
    float s = 0.f;
#pragma unroll
    for (int f = 0; f < 9; ++f) s += emb[(size_t)xi[f] * DD + t];
    h[(size_t)n * DD + t] = s;
}

// ---------------- Message + scatter: agg[dst] += relu(h[src] + bond_e) ----------------
__global__ __launch_bounds__(320) void msg_kernel(const float* __restrict__ h,
    const int* __restrict__ src, const int* __restrict__ dst,
    const int* __restrict__ ea, const float* __restrict__ bond,
    float* __restrict__ agg, int E)
{
    __shared__ int meta[8][5];  // src, dst, 3 bond-row indices
    int e0 = blockIdx.x * 8;
    int t = threadIdx.x;
    if (t < 40) {
        int ei = t / 5, f = t % 5;
        int e = e0 + ei;
        int v = 0;
        if (e < E) {
            if (f == 0) v = src[e];
            else if (f == 1) v = dst[e];
            else v = ea[e * 3 + (f - 2)] + (f - 2) * 8;
        }
        meta[ei][f] = v;
    }
    __syncthreads();
    int d = t;
    if (d >= DD) return;
    for (int ei = 0; ei < 8; ++ei) {
        int e = e0 + ei;
        if (e >= E) break;
        int s = meta[ei][0], dn = meta[ei][1];
        float ev = bond[(size_t)meta[ei][2] * DD + d]
                 + bond[(size_t)meta[ei][3] * DD + d]
                 + bond[(size_t)meta[ei][4] * DD + d];
        float m = h[(size_t)s * DD + d] + ev;
        m = fmaxf(m, 0.f);
        atomicAdd(&agg[(size_t)dn * DD + d], m);
    }
}

// ---------------- z = (1+eps[l])*h + agg  (in place over agg) ----------------
__global__ void z_kernel(const float* __restrict__ h, float* __restrict__ zb,
                         const float* __restrict__ eps, int l, int n4)
{
    float s = 1.0f + eps[l];
    int i = blockIdx.x * blockDim.x + threadIdx.x;
    int stride = gridDim.x * blockDim.x;
    const float4* h4 = (const float4*)h;
    float4* z4 = (float4*)zb;
    for (; i < n4; i += stride) {
        float4 a = h4[i], b = z4[i];
        b.x = fmaf(s, a.x, b.x);
        b.y = fmaf(s, a.y, b.y);
        b.z = fmaf(s, a.z, b.z);
        b.w = fmaf(s, a.w, b.w);
        z4[i] = b;
    }
}

// ---------------- fp32 GEMM: C[M,N] = op(A)[M,K] @ B[K,N] + bias ----------------
// op(A) = FUSE_A ? relu(A*ascale[k]+ashift[k]) : A   (fused BN1+ReLU for GEMM2)
template <bool FUSE_A>
__global__ __launch_bounds__(256) void gemm128(const float* __restrict__ A,
    const float* __restrict__ B, const float* __restrict__ bias,
    float* __restrict__ C, int M, int N, int K,
    const float* __restrict__ ascale, const float* __restrict__ ashift)
{
    __shared__ float As[16][132];
    __shared__ float Bs[16][132];
    const int row0 = blockIdx.x * 128;
    const int col0 = blockIdx.y * 128;
    const int t = threadIdx.x;
    const int tx = t & 15, ty = t >> 4;
    float acc[8][8] = {};

    for (int k0 = 0; k0 < K; k0 += 16) {
        // A tile 128x16, float4 along k, store transposed into As[k][m]
#pragma unroll
        for (int i = 0; i < 2; ++i) {
            int idx = t + i * 256;       // 0..511
            int m = idx >> 2;            // 0..127
            int k4 = (idx & 3) * 4;
            int gr = row0 + m, gk = k0 + k4;
            float4 v = {0.f, 0.f, 0.f, 0.f};
            if (gr < M && gk + 3 < K) {
                v = *(const float4*)(A + (size_t)gr * K + gk);
                if (FUSE_A) {
                    v.x = fmaxf(fmaf(v.x, ascale[gk],     ashift[gk]),     0.f);
                    v.y = fmaxf(fmaf(v.y, ascale[gk + 1], ashift[gk + 1]), 0.f);
                    v.z = fmaxf(fmaf(v.z, ascale[gk + 2], ashift[gk + 2]), 0.f);
                    v.w = fmaxf(fmaf(v.w, ascale[gk + 3], ashift[gk + 3]), 0.f);
                }
            }
            As[k4 + 0][m] = v.x;
            As[k4 + 1][m] = v.y;
            As[k4 + 2][m] = v.z;
            As[k4 + 3][m] = v.w;
        }
        // B tile 16x128, float4 along n
#pragma unroll
        for (int i = 0; i < 2; ++i) {
            int idx = t + i * 256;       // 0..511
            int k = idx >> 5;            // 0..15
            int n4 = (idx & 31) * 4;
            int gk = k0 + k, gc = col0 + n4;
            float4 v = {0.f, 0.f, 0.f, 0.f};
            if (gk < K && gc + 3 < N) v = *(const float4*)(B + (size_t)gk * N + gc);
            *(float4*)&Bs[k][n4] = v;
        }
        __syncthreads();
#pragma unroll
        for (int k = 0; k < 16; ++k) {
            float4 a0 = *(const float4*)&As[k][ty * 8];
            float4 a1 = *(const float4*)&As[k][ty * 8 + 4];
            float4 b0 = *(const float4*)&Bs[k][tx * 8];
            float4 b1 = *(const float4*)&Bs[k][tx * 8 + 4];
            float ra[8] = {a0.x, a0.y, a0.z, a0.w, a1.x, a1.y, a1.z, a1.w};
            float rb[8] = {b0.x, b0.y, b0.z, b0.w, b1.x, b1.y, b1.z, b1.w};
#pragma unroll
            for (int i = 0; i < 8; ++i)
#pragma unroll
                for (int j = 0; j < 8; ++j)
                    acc[i][j] = fmaf(ra[i], rb[j], acc[i][j]);
        }
        __syncthreads();
    }
    // epilogue: C = acc + bias
#pragma unroll
    for (int i = 0; i < 8; ++i) {
        int gr = row0 + ty * 8 + i;
        if (gr >= M) continue;
#pragma unroll
        for (int j4 = 0; j4 < 8; j4 += 4) {
            int gc = col0 + tx * 8 + j4;
            if (gc + 3 < N) {
                float4 o;
                o.x = acc[i][j4 + 0] + bias[gc + 0];
                o.y = acc[i][j4 + 1] + bias[gc + 1];
                o.z = acc[i][j4 + 2] + bias[gc + 2];
                o.w = acc[i][j4 + 3] + bias[gc + 3];
                *(float4*)(C + (size_t)gr * N + gc) = o;
            }
        }
    }
}

// ---------------- column sums / sums-of-squares for BatchNorm stats ----------------
__global__ __launch_bounds__(256) void colstats(const float* __restrict__ Mx,
    int rows, int cols, float* __restrict__ cs, float* __restrict__ csq, int rpb)
{
    int r0 = blockIdx.x * rpb;
    int r1 = min(r0 + rpb, rows);
    int t = threadIdx.x;
    float s[3] = {0.f, 0.f, 0.f}, q[3] = {0.f, 0.f, 0.f};
    for (int r = r0; r < r1; ++r) {
        const float* row = Mx + (size_t)r * cols;
#pragma unroll
        for (int ci = 0; ci < 3; ++ci) {
            int c = t + ci * 256;
            if (c < cols) { float v = row[c]; s[ci] += v; q[ci] += v * v; }
        }
    }
#pragma unroll
    for (int ci = 0; ci < 3; ++ci) {
        int c = t + ci * 256;
        if (c < cols) { atomicAdd(&cs[c], s[ci]); atomicAdd(&csq[c], q[ci]); }
    }
}

// ---------------- finalize BN: scale = gamma*rsqrt(var+eps), shift = beta - mu*scale ----
__global__ void bn_fin(const float* __restrict__ cs, const float* __restrict__ csq,
                       const float* __restrict__ g, const float* __restrict__ be,
                       float* __restrict__ scale, float* __restrict__ shift,
                       int cols, float invn)
{
    int c = blockIdx.x * blockDim.x + threadIdx.x;
    if (c >= cols) return;
    float mu = cs[c] * invn;
    float var = csq[c] * invn - mu * mu;
    float rs = rsqrtf(var + 1e-5f);
    float sc = rs * g[c];
    scale[c] = sc;
    shift[c] = be[c] - mu * sc;
}

// ---------------- apply BN (+optional ReLU) elementwise: h = Z*scale[c]+shift[c] ----------------
__global__ void bn_apply(const float* __restrict__ Z, float* __restrict__ H,
                         const float* __restrict__ scale, const float* __restrict__ shift,
                         int n4, int relu)
{
    int i = blockIdx.x * blockDim.x + threadIdx.x;
    int stride = gridDim.x * blockDim.x;
    for (; i < n4; i += stride) {
        float4 v = ((const float4*)Z)[i];
        int c0 = (i * 4) % DD;   // 300 % 4 == 0 -> quad never crosses a row
        float4 o;
        o.x = fmaf(v.x, scale[c0 + 0], shift[c0 + 0]);
        o.y = fmaf(v.y, scale[c0 + 1], shift[c0 + 1]);
        o.z = fmaf(v.z, scale[c0 + 2], shift[c0 + 2]);
        o.w = fmaf(v.w, scale[c0 + 3], shift[c0 + 3]);
        if (relu) {
            o.x = fmaxf(o.x, 0.f); o.y = fmaxf(o.y, 0.f);
            o.z = fmaxf(o.z, 0.f); o.w = fmaxf(o.w, 0.f);
        }
        ((float4*)H)[i] = o;
    }
}

// ---------------- global_add_pool via sorted-batch range reduction ----------------
__global__ __launch_bounds__(320) void pool_kernel(const float* __restrict__ h,
    const int* __restrict__ batch, int N, float* __restrict__ hg)
{
    int g = blockIdx.x;
    int lo = 0, hi = N;
    while (lo < hi) { int mid = (lo + hi) >> 1; if (batch[mid] < g) lo = mid + 1; else hi = mid; }
    int start = lo;
    hi = N;
    while (lo < hi) { int mid = (lo + hi) >> 1; if (batch[mid] <= g) lo = mid + 1; else hi = mid; }
    int end = lo;
    int d = threadIdx.x;
    if (d >= DD) return;
    float s = 0.f;
    for (int i = start; i < end; ++i) s += h[(size_t)i * DD + d];
    hg[(size_t)g * DD + d] = s;
}

// ---------------- GroupNorm(1 group, no affine) + linear head ----------------
__global__ __launch_bounds__(256) void head_kernel(const float* __restrict__ hg,
    const float* __restrict__ w, const float* __restrict__ b, float* __restrict__ out)
{
    __shared__ float red[256];
    int g = blockIdx.x, t = threadIdx.x;
    const float* row = hg + (size_t)g * DD;
    float v0 = (t < DD) ? row[t] : 0.f;
    float v1 = (t + 256 < DD) ? row[t + 256] : 0.f;

    red[t] = v0 + v1;
    __syncthreads();
    for (int o = 128; o > 0; o >>= 1) { if (t < o) red[t] += red[t + o]; __syncthreads(); }
    float mean = red[0] * (1.f / (float)DD);
    __syncthreads();

    red[t] = v0 * v0 + v1 * v1;
    __syncthreads();
    for (int o = 128; o > 0; o >>= 1) { if (t < o) red[t] += red[t + o]; __syncthreads(); }
    float var = red[0] * (1.f / (float)DD) - mean * mean;
    float rs = rsqrtf(var + 1e-5f);
    __syncthreads();

    float d0 = (t < DD) ? (v0 - mean) * rs * w[t] : 0.f;
    float d1 = (t + 256 < DD) ? (v1 - mean) * rs * w[t + 256] : 0.f;
    red[t] = d0 + d1;
    __syncthreads();
    for (int o = 128; o > 0; o >>= 1) { if (t < o) red[t] += red[t + o]; __syncthreads(); }
    if (t == 0) out[g] = red[0] + b[0];
}

extern "C" void kernel_launch(void* const* d_in, const int* in_sizes, int n_in,
                              void* d_out, int out_size, void* d_ws, size_t ws_size,
                              hipStream_t stream)
{
    (void)n_in; (void)out_size; (void)ws_size;
    const int*   x         = (const int*)  d_in[0];
    const int*   edge_idx  = (const int*)  d_in[1];
    const int*   edge_attr = (const int*)  d_in[2];
    const int*   batch     = (const int*)  d_in[3];
    const float* atom_emb  = (const float*)d_in[4];
    const float* bond_emb  = (const float*)d_in[5];
    const float* eps       = (const float*)d_in[6];
    const float* W1        = (const float*)d_in[7];
    const float* b1        = (const float*)d_in[8];
    const float* g1        = (const float*)d_in[9];
    const float* be1       = (const float*)d_in[10];
    const float* W2        = (const float*)d_in[11];
    const float* b2        = (const float*)d_in[12];
    const float* g2        = (const float*)d_in[13];
    const float* be2       = (const float*)d_in[14];
    const float* head_w    = (const float*)d_in[15];
    const float* head_b    = (const float*)d_in[16];

    const int N = in_sizes[3];
    const int E = in_sizes[1] / 2;

    float* ws  = (float*)d_ws;
    float* h   = ws;                         // N*300
    float* zb  = h  + (size_t)N * DD;        // N*300 (agg -> z -> Z2)
    float* Z1  = zb + (size_t)N * DD;        // N*600
    float* hg  = Z1 + (size_t)N * HH;        // 512*300
    float* cs  = hg + (size_t)NGG * DD;      // 600
    float* csq = cs + HH;
    float* sc1 = csq + HH;
    float* sh1 = sc1 + HH;
    float* sc2 = sh1 + HH;
    float* sh2 = sc2 + DD;

    atom_kernel<<<N, 320, 0, stream>>>(x, atom_emb, h, N);

    const int gm = (N + 127) / 128;
    for (int l = 0; l < LL; ++l) {
        hipMemsetAsync(zb, 0, (size_t)N * DD * sizeof(float), stream);
        msg_kernel<<<(E + 7) / 8, 320, 0, stream>>>(h, edge_idx, edge_idx + E,
            edge_attr, bond_emb + (size_t)l * 24 * DD, zb, E);
        z_kernel<<<1024, 256, 0, stream>>>(h, zb, eps, l, N * DD / 4);

        gemm128<false><<<dim3(gm, (HH + 127) / 128), 256, 0, stream>>>(
            zb, W1 + (size_t)l * DD * HH, b1 + (size_t)l * HH, Z1, N, HH, DD, nullptr, nullptr);

        hipMemsetAsync(cs, 0, HH * sizeof(float), stream);
        hipMemsetAsync(csq, 0, HH * sizeof(float), stream);
        colstats<<<(N + 63) / 64, 256, 0, stream>>>(Z1, N, HH, cs, csq, 64);
        bn_fin<<<(HH + 255) / 256, 256, 0, stream>>>(cs, csq, g1 + (size_t)l * HH,
            be1 + (size_t)l * HH, sc1, sh1, HH, 1.f / (float)N);

        gemm128<true><<<dim3(gm, (DD + 127) / 128), 256, 0, stream>>>(
            Z1, W2 + (size_t)l * HH * DD, b2 + (size_t)l * DD, zb, N, DD, HH, sc1, sh1);

        hipMemsetAsync(cs, 0, DD * sizeof(float), stream);
        hipMemsetAsync(csq, 0, DD * sizeof(float), stream);
        colstats<<<(N + 63) / 64, 256, 0, stream>>>(zb, N, DD, cs, csq, 64);
        bn_fin<<<(DD + 255) / 256, 256, 0, stream>>>(cs, csq, g2 + (size_t)l * DD,
            be2 + (size_t)l * DD, sc2, sh2, DD, 1.f / (float)N);

        bn_apply<<<1024, 256, 0, stream>>>(zb, h, sc2, sh2, N * DD / 4, (l < LL - 1) ? 1 : 0);
    }

    pool_kernel<<<NGG, 320, 0, stream>>>(h, batch, N, hg);
    head_kernel<<<NGG, 256, 0, stream>>>(hg, head_w, head_b, (float*)d_out);
}

// Round 2
// 2616.769 us; speedup vs baseline: 1.4897x; 1.4897x over previous
//
#include <hip/hip_runtime.h>
#include <cstddef>

#define DD 300
#define HH 600
#define LL 5
#define NGG 512

// ---------------- Atom encoder: h[n,d] = sum_f atom_emb[x[n,f]+64f][d] ----------------
__global__ __launch_bounds__(320) void atom_kernel(const int* __restrict__ x,
    const float* __restrict__ emb, float* __restrict__ h, int N)
{
    __shared__ int xi[9];
    int n = blockIdx.x;
    int t = threadIdx.x;
    if (t < 9) xi[t] = x[n * 9 + t] + t * 64;
    __syncthreads();
    if (t >= DD) return;
    float s = 0.f;
#pragma unroll
    for (int f = 0; f < 9; ++f) s += emb[(size_t)xi[f] * DD + t];
    h[(size_t)n * DD + t] = s;
}

// ---------------- CSR build: histogram of dst ----------------
__global__ void csr_count(const int* __restrict__ dst, int E, int* __restrict__ cnt)
{
    int i = blockIdx.x * blockDim.x + threadIdx.x;
    int stride = gridDim.x * blockDim.x;
    for (; i < E; i += stride) atomicAdd(&cnt[dst[i]], 1);
}

// ---------------- CSR build: single-block exclusive scan over cnt[n] -> rowptr[n+1] ----
__global__ __launch_bounds__(1024) void scan_kernel(const int* __restrict__ cnt,
    int* __restrict__ rowptr, int n)
{
    __shared__ int buf[1024];
    int t = threadIdx.x;
    int carry = 0;
    for (int base = 0; base < n; base += 1024) {
        int v = (base + t < n) ? cnt[base + t] : 0;
        buf[t] = v;
        __syncthreads();
        for (int off = 1; off < 1024; off <<= 1) {
            int x = (t >= off) ? buf[t - off] : 0;
            __syncthreads();
            buf[t] += x;
            __syncthreads();
        }
        if (base + t < n) rowptr[base + t] = buf[t] - v + carry;
        int total = buf[1023];
        __syncthreads();
        carry += total;
    }
    if (t == 0) rowptr[n] = carry;
}

// ---------------- CSR build: scatter edges into buckets, pack src+bond code ----------
__global__ void csr_fill(const int* __restrict__ src, const int* __restrict__ dst,
    const int* __restrict__ ea, const int* __restrict__ rowptr,
    int* __restrict__ cursor, int* __restrict__ rec, int E)
{
    int i = blockIdx.x * blockDim.x + threadIdx.x;
    int stride = gridDim.x * blockDim.x;
    for (; i < E; i += stride) {
        int d = dst[i];
        int pos = rowptr[d] + atomicAdd(&cursor[d], 1);
        int code = ea[i * 3] | (ea[i * 3 + 1] << 3) | (ea[i * 3 + 2] << 6);
        rec[pos] = src[i] | (code << 20);
    }
}

// ---------------- per-layer bond-code combo table: combo[l][code][d] ----------------
__global__ __launch_bounds__(320) void combo_build(const float* __restrict__ bond,
    float* __restrict__ combo)
{
    int blk = blockIdx.x;           // l*512 + code
    int l = blk >> 9, code = blk & 511;
    int t = threadIdx.x;
    if (t >= DD) return;
    const float* bl = bond + (size_t)l * 24 * DD;
    combo[(size_t)blk * DD + t] = bl[(size_t)(code & 7) * DD + t]
                                + bl[(size_t)(8 + ((code >> 3) & 7)) * DD + t]
                                + bl[(size_t)(16 + (code >> 6)) * DD + t];
}

// ---------------- fused aggregate + GIN update: zb[n] = (1+eps)h[n] + sum relu(h[src]+combo[code]) ----
__global__ __launch_bounds__(320) void agg_kernel(const float* __restrict__ h,
    const int* __restrict__ rec, const int* __restrict__ rowptr,
    const float* __restrict__ combo_l, const float* __restrict__ eps, int l,
    float* __restrict__ zb)
{
    int n = blockIdx.x;
    int t = threadIdx.x;
    if (t >= DD) return;
    int beg = rowptr[n], end = rowptr[n + 1];
    float acc = 0.f;
    for (int i = beg; i < end; ++i) {
        int r = rec[i];
        int s = r & 0xFFFFF;
        int code = ((unsigned)r) >> 20;
        float v = h[(size_t)s * DD + t] + combo_l[(size_t)code * DD + t];
        acc += fmaxf(v, 0.f);
    }
    float se = 1.0f + eps[l];
    zb[(size_t)n * DD + t] = fmaf(se, h[(size_t)n * DD + t], acc);
}

// ---------------- fp32 GEMM: C[M,N] = op(A)[M,K] @ B[K,N] + bias ----------------
// op(A) = FUSE_A ? relu(A*ascale[k]+ashift[k]) : A   (fused BN1+ReLU for GEMM2)
template <bool FUSE_A>
__global__ __launch_bounds__(256) void gemm128(const float* __restrict__ A,
    const float* __restrict__ B, const float* __restrict__ bias,
    float* __restrict__ C, int M, int N, int K,
    const float* __restrict__ ascale, const float* __restrict__ ashift)
{
    __shared__ float As[16][132];
    __shared__ float Bs[16][132];
    const int row0 = blockIdx.x * 128;
    const int col0 = blockIdx.y * 128;
    const int t = threadIdx.x;
    const int tx = t & 15, ty = t >> 4;
    float acc[8][8] = {};

    for (int k0 = 0; k0 < K; k0 += 16) {
#pragma unroll
        for (int i = 0; i < 2; ++i) {
            int idx = t + i * 256;
            int m = idx >> 2;
            int k4 = (idx & 3) * 4;
            int gr = row0 + m, gk = k0 + k4;
            float4 v = {0.f, 0.f, 0.f, 0.f};
            if (gr < M && gk + 3 < K) {
                v = *(const float4*)(A + (size_t)gr * K + gk);
                if (FUSE_A) {
                    v.x = fmaxf(fmaf(v.x, ascale[gk],     ashift[gk]),     0.f);
                    v.y = fmaxf(fmaf(v.y, ascale[gk + 1], ashift[gk + 1]), 0.f);
                    v.z = fmaxf(fmaf(v.z, ascale[gk + 2], ashift[gk + 2]), 0.f);
                    v.w = fmaxf(fmaf(v.w, ascale[gk + 3], ashift[gk + 3]), 0.f);
                }
            }
            As[k4 + 0][m] = v.x;
            As[k4 + 1][m] = v.y;
            As[k4 + 2][m] = v.z;
            As[k4 + 3][m] = v.w;
        }
#pragma unroll
        for (int i = 0; i < 2; ++i) {
            int idx = t + i * 256;
            int k = idx >> 5;
            int n4 = (idx & 31) * 4;
            int gk = k0 + k, gc = col0 + n4;
            float4 v = {0.f, 0.f, 0.f, 0.f};
            if (gk < K && gc + 3 < N) v = *(const float4*)(B + (size_t)gk * N + gc);
            *(float4*)&Bs[k][n4] = v;
        }
        __syncthreads();
#pragma unroll
        for (int k = 0; k < 16; ++k) {
            float4 a0 = *(const float4*)&As[k][ty * 8];
            float4 a1 = *(const float4*)&As[k][ty * 8 + 4];
            float4 b0 = *(const float4*)&Bs[k][tx * 8];
            float4 b1 = *(const float4*)&Bs[k][tx * 8 + 4];
            float ra[8] = {a0.x, a0.y, a0.z, a0.w, a1.x, a1.y, a1.z, a1.w};
            float rb[8] = {b0.x, b0.y, b0.z, b0.w, b1.x, b1.y, b1.z, b1.w};
#pragma unroll
            for (int i = 0; i < 8; ++i)
#pragma unroll
                for (int j = 0; j < 8; ++j)
                    acc[i][j] = fmaf(ra[i], rb[j], acc[i][j]);
        }
        __syncthreads();
    }
#pragma unroll
    for (int i = 0; i < 8; ++i) {
        int gr = row0 + ty * 8 + i;
        if (gr >= M) continue;
#pragma unroll
        for (int j4 = 0; j4 < 8; j4 += 4) {
            int gc = col0 + tx * 8 + j4;
            if (gc + 3 < N) {
                float4 o;
                o.x = acc[i][j4 + 0] + bias[gc + 0];
                o.y = acc[i][j4 + 1] + bias[gc + 1];
                o.z = acc[i][j4 + 2] + bias[gc + 2];
                o.w = acc[i][j4 + 3] + bias[gc + 3];
                *(float4*)(C + (size_t)gr * N + gc) = o;
            }
        }
    }
}

// ---------------- column sums / sums-of-squares for BatchNorm stats ----------------
__global__ __launch_bounds__(256) void colstats(const float* __restrict__ Mx,
    int rows, int cols, float* __restrict__ cs, float* __restrict__ csq, int rpb)
{
    int r0 = blockIdx.x * rpb;
    int r1 = min(r0 + rpb, rows);
    int t = threadIdx.x;
    float s[3] = {0.f, 0.f, 0.f}, q[3] = {0.f, 0.f, 0.f};
    for (int r = r0; r < r1; ++r) {
        const float* row = Mx + (size_t)r * cols;
#pragma unroll
        for (int ci = 0; ci < 3; ++ci) {
            int c = t + ci * 256;
            if (c < cols) { float v = row[c]; s[ci] += v; q[ci] += v * v; }
        }
    }
#pragma unroll
    for (int ci = 0; ci < 3; ++ci) {
        int c = t + ci * 256;
        if (c < cols) { atomicAdd(&cs[c], s[ci]); atomicAdd(&csq[c], q[ci]); }
    }
}

// ---------------- finalize BN: scale = gamma*rsqrt(var+eps), shift = beta - mu*scale ----
__global__ void bn_fin(const float* __restrict__ cs, const float* __restrict__ csq,
                       const float* __restrict__ g, const float* __restrict__ be,
                       float* __restrict__ scale, float* __restrict__ shift,
                       int cols, float invn)
{
    int c = blockIdx.x * blockDim.x + threadIdx.x;
    if (c >= cols) return;
    float mu = cs[c] * invn;
    float var = csq[c] * invn - mu * mu;
    float rs = rsqrtf(var + 1e-5f);
    float sc = rs * g[c];
    scale[c] = sc;
    shift[c] = be[c] - mu * sc;
}

// ---------------- apply BN (+optional ReLU): h = Z*scale[c]+shift[c] ----------------
__global__ void bn_apply(const float* __restrict__ Z, float* __restrict__ H,
                         const float* __restrict__ scale, const float* __restrict__ shift,
                         int n4, int relu)
{
    int i = blockIdx.x * blockDim.x + threadIdx.x;
    int stride = gridDim.x * blockDim.x;
    for (; i < n4; i += stride) {
        float4 v = ((const float4*)Z)[i];
        int c0 = (i * 4) % DD;   // 300 % 4 == 0 -> quad never crosses a row
        float4 o;
        o.x = fmaf(v.x, scale[c0 + 0], shift[c0 + 0]);
        o.y = fmaf(v.y, scale[c0 + 1], shift[c0 + 1]);
        o.z = fmaf(v.z, scale[c0 + 2], shift[c0 + 2]);
        o.w = fmaf(v.w, scale[c0 + 3], shift[c0 + 3]);
        if (relu) {
            o.x = fmaxf(o.x, 0.f); o.y = fmaxf(o.y, 0.f);
            o.z = fmaxf(o.z, 0.f); o.w = fmaxf(o.w, 0.f);
        }
        ((float4*)H)[i] = o;
    }
}

// ---------------- global_add_pool via sorted-batch range reduction ----------------
__global__ __launch_bounds__(320) void pool_kernel(const float* __restrict__ h,
    const int* __restrict__ batch, int N, float* __restrict__ hg)
{
    int g = blockIdx.x;
    int lo = 0, hi = N;
    while (lo < hi) { int mid = (lo + hi) >> 1; if (batch[mid] < g) lo = mid + 1; else hi = mid; }
    int start = lo;
    hi = N;
    while (lo < hi) { int mid = (lo + hi) >> 1; if (batch[mid] <= g) lo = mid + 1; else hi = mid; }
    int end = lo;
    int d = threadIdx.x;
    if (d >= DD) return;
    float s = 0.f;
    for (int i = start; i < end; ++i) s += h[(size_t)i * DD + d];
    hg[(size_t)g * DD + d] = s;
}

// ---------------- GroupNorm(1 group, no affine) + linear head ----------------
__global__ __launch_bounds__(256) void head_kernel(const float* __restrict__ hg,
    const float* __restrict__ w, const float* __restrict__ b, float* __restrict__ out)
{
    __shared__ float red[256];
    int g = blockIdx.x, t = threadIdx.x;
    const float* row = hg + (size_t)g * DD;
    float v0 = (t < DD) ? row[t] : 0.f;
    float v1 = (t + 256 < DD) ? row[t + 256] : 0.f;

    red[t] = v0 + v1;
    __syncthreads();
    for (int o = 128; o > 0; o >>= 1) { if (t < o) red[t] += red[t + o]; __syncthreads(); }
    float mean = red[0] * (1.f / (float)DD);
    __syncthreads();

    red[t] = v0 * v0 + v1 * v1;
    __syncthreads();
    for (int o = 128; o > 0; o >>= 1) { if (t < o) red[t] += red[t + o]; __syncthreads(); }
    float var = red[0] * (1.f / (float)DD) - mean * mean;
    float rs = rsqrtf(var + 1e-5f);
    __syncthreads();

    float d0 = (t < DD) ? (v0 - mean) * rs * w[t] : 0.f;
    float d1 = (t + 256 < DD) ? (v1 - mean) * rs * w[t + 256] : 0.f;
    red[t] = d0 + d1;
    __syncthreads();
    for (int o = 128; o > 0; o >>= 1) { if (t < o) red[t] += red[t + o]; __syncthreads(); }
    if (t == 0) out[g] = red[0] + b[0];
}

extern "C" void kernel_launch(void* const* d_in, const int* in_sizes, int n_in,
                              void* d_out, int out_size, void* d_ws, size_t ws_size,
                              hipStream_t stream)
{
    (void)n_in; (void)out_size; (void)ws_size;
    const int*   x         = (const int*)  d_in[0];
    const int*   edge_idx  = (const int*)  d_in[1];
    const int*   edge_attr = (const int*)  d_in[2];
    const int*   batch     = (const int*)  d_in[3];
    const float* atom_emb  = (const float*)d_in[4];
    const float* bond_emb  = (const float*)d_in[5];
    const float* eps       = (const float*)d_in[6];
    const float* W1        = (const float*)d_in[7];
    const float* b1        = (const float*)d_in[8];
    const float* g1        = (const float*)d_in[9];
    const float* be1       = (const float*)d_in[10];
    const float* W2        = (const float*)d_in[11];
    const float* b2        = (const float*)d_in[12];
    const float* g2        = (const float*)d_in[13];
    const float* be2       = (const float*)d_in[14];
    const float* head_w    = (const float*)d_in[15];
    const float* head_b    = (const float*)d_in[16];

    const int N = in_sizes[3];
    const int E = in_sizes[1] / 2;

    float* ws  = (float*)d_ws;
    float* h     = ws;                         // N*300
    float* zb    = h  + (size_t)N * DD;        // N*300
    float* Z1    = zb + (size_t)N * DD;        // N*600
    float* hg    = Z1 + (size_t)N * HH;        // 512*300
    float* cs    = hg + (size_t)NGG * DD;      // 600
    float* csq   = cs + HH;
    float* sc1   = csq + HH;
    float* sh1   = sc1 + HH;
    float* sc2   = sh1 + HH;
    float* sh2   = sc2 + DD;
    float* combo = sh2 + DD;                   // 5*512*300
    int* cnt     = (int*)(combo + (size_t)LL * 512 * DD);   // N
    int* cursor  = cnt + N;                    // N
    int* rowptr  = cursor + N;                 // N+1
    int* rec     = rowptr + N + 1;             // E

    const int* src = edge_idx;
    const int* dst = edge_idx + E;

    // ---- one-time per call: CSR + bond combo tables ----
    hipMemsetAsync(cnt, 0, (size_t)N * sizeof(int), stream);
    hipMemsetAsync(cursor, 0, (size_t)N * sizeof(int), stream);
    csr_count<<<512, 256, 0, stream>>>(dst, E, cnt);
    scan_kernel<<<1, 1024, 0, stream>>>(cnt, rowptr, N);
    csr_fill<<<512, 256, 0, stream>>>(src, dst, edge_attr, rowptr, cursor, rec, E);
    combo_build<<<LL * 512, 320, 0, stream>>>(bond_emb, combo);

    atom_kernel<<<N, 320, 0, stream>>>(x, atom_emb, h, N);

    const int gm = (N + 127) / 128;
    for (int l = 0; l < LL; ++l) {
        agg_kernel<<<N, 320, 0, stream>>>(h, rec, rowptr,
            combo + (size_t)l * 512 * DD, eps, l, zb);

        gemm128<false><<<dim3(gm, (HH + 127) / 128), 256, 0, stream>>>(
            zb, W1 + (size_t)l * DD * HH, b1 + (size_t)l * HH, Z1, N, HH, DD, nullptr, nullptr);

        hipMemsetAsync(cs, 0, HH * sizeof(float), stream);
        hipMemsetAsync(csq, 0, HH * sizeof(float), stream);
        colstats<<<(N + 63) / 64, 256, 0, stream>>>(Z1, N, HH, cs, csq, 64);
        bn_fin<<<(HH + 255) / 256, 256, 0, stream>>>(cs, csq, g1 + (size_t)l * HH,
            be1 + (size_t)l * HH, sc1, sh1, HH, 1.f / (float)N);

        gemm128<true><<<dim3(gm, (DD + 127) / 128), 256, 0, stream>>>(
            Z1, W2 + (size_t)l * HH * DD, b2 + (size_t)l * DD, zb, N, DD, HH, sc1, sh1);

        hipMemsetAsync(cs, 0, DD * sizeof(float), stream);
        hipMemsetAsync(csq, 0, DD * sizeof(float), stream);
        colstats<<<(N + 63) / 64, 256, 0, stream>>>(zb, N, DD, cs, csq, 64);
        bn_fin<<<(DD + 255) / 256, 256, 0, stream>>>(cs, csq, g2 + (size_t)l * DD,
            be2 + (size_t)l * DD, sc2, sh2, DD, 1.f / (float)N);

        bn_apply<<<1024, 256, 0, stream>>>(zb, h, sc2, sh2, N * DD / 4, (l < LL - 1) ? 1 : 0);
    }

    pool_kernel<<<NGG, 320, 0, stream>>>(h, batch, N, hg);
    head_kernel<<<NGG, 256, 0, stream>>>(hg, head_w, head_b, (float*)d_out);
}

// Round 3
// 2021.936 us; speedup vs baseline: 1.9280x; 1.2942x over previous
//
#include <hip/hip_runtime.h>
#include <cstddef>
#include <cstdint>

#define DD 300
#define HH 600
#define LL 5
#define NGG 512
#define KP1 320     // padded K for GEMM1 (D=300 -> 10 K-steps of 32)
#define KP2 608     // padded K for GEMM2 (H=600 -> 19 K-steps of 32)
#define NP1 640     // padded N-rows of W1^T (600 -> 5 col-blocks of 128)
#define NP2 384     // padded N-rows of W2^T (300 -> 3 col-blocks of 128)

typedef unsigned short u16;
typedef short bf16x8 __attribute__((ext_vector_type(8)));
typedef float f32x4 __attribute__((ext_vector_type(4)));

__device__ __forceinline__ float bf2f(u16 h) { return __uint_as_float(((unsigned)h) << 16); }

// RNE split: v = hi + lo (two bf16, ~16 mantissa bits total)
__device__ __forceinline__ void split2(float v, u16& hi, u16& lo)
{
    unsigned u = __float_as_uint(v);
    unsigned r = (u + 0x7FFFu + ((u >> 16) & 1u)) >> 16;
    hi = (u16)r;
    float res = v - __uint_as_float(r << 16);
    unsigned u2 = __float_as_uint(res);
    lo = (u16)((u2 + 0x7FFFu + ((u2 >> 16) & 1u)) >> 16);
}

__device__ __forceinline__ void g2l16(const void* g, void* l)
{
    __builtin_amdgcn_global_load_lds(
        (const __attribute__((address_space(1))) void*)g,
        (__attribute__((address_space(3))) void*)l, 16, 0, 0);
}

// ---------------- Atom encoder ----------------
__global__ __launch_bounds__(320) void atom_kernel(const int* __restrict__ x,
    const float* __restrict__ emb, float* __restrict__ h, int N)
{
    __shared__ int xi[9];
    int n = blockIdx.x;
    int t = threadIdx.x;
    if (t < 9) xi[t] = x[n * 9 + t] + t * 64;
    __syncthreads();
    if (t >= DD) return;
    float s = 0.f;
#pragma unroll
    for (int f = 0; f < 9; ++f) s += emb[(size_t)xi[f] * DD + t];
    h[(size_t)n * DD + t] = s;
}

// ---------------- CSR build ----------------
__global__ void csr_count(const int* __restrict__ dst, int E, int* __restrict__ cnt)
{
    int i = blockIdx.x * blockDim.x + threadIdx.x;
    int stride = gridDim.x * blockDim.x;
    for (; i < E; i += stride) atomicAdd(&cnt[dst[i]], 1);
}

__global__ __launch_bounds__(1024) void scan_kernel(const int* __restrict__ cnt,
    int* __restrict__ rowptr, int n)
{
    __shared__ int buf[1024];
    int t = threadIdx.x;
    int carry = 0;
    for (int base = 0; base < n; base += 1024) {
        int v = (base + t < n) ? cnt[base + t] : 0;
        buf[t] = v;
        __syncthreads();
        for (int off = 1; off < 1024; off <<= 1) {
            int x = (t >= off) ? buf[t - off] : 0;
            __syncthreads();
            buf[t] += x;
            __syncthreads();
        }
        if (base + t < n) rowptr[base + t] = buf[t] - v + carry;
        int total = buf[1023];
        __syncthreads();
        carry += total;
    }
    if (t == 0) rowptr[n] = carry;
}

__global__ void csr_fill(const int* __restrict__ src, const int* __restrict__ dst,
    const int* __restrict__ ea, const int* __restrict__ rowptr,
    int* __restrict__ cursor, int* __restrict__ rec, int E)
{
    int i = blockIdx.x * blockDim.x + threadIdx.x;
    int stride = gridDim.x * blockDim.x;
    for (; i < E; i += stride) {
        int d = dst[i];
        int pos = rowptr[d] + atomicAdd(&cursor[d], 1);
        int code = ea[i * 3] | (ea[i * 3 + 1] << 3) | (ea[i * 3 + 2] << 6);
        rec[pos] = src[i] | (code << 20);
    }
}

// ---------------- per-layer bond-code combo table ----------------
__global__ __launch_bounds__(320) void combo_build(const float* __restrict__ bond,
    float* __restrict__ combo)
{
    int blk = blockIdx.x;           // l*512 + code
    int l = blk >> 9, code = blk & 511;
    int t = threadIdx.x;
    if (t >= DD) return;
    const float* bl = bond + (size_t)l * 24 * DD;
    combo[(size_t)blk * DD + t] = bl[(size_t)(code & 7) * DD + t]
                                + bl[(size_t)(8 + ((code >> 3) & 7)) * DD + t]
                                + bl[(size_t)(16 + (code >> 6)) * DD + t];
}

// ---------------- weight transpose + bf16-split, zero-padded ----------------
// W [L][K][N] fp32 -> T [L][NPp][KPp] bf16 hi/lo with T[l][n][k] = W[l][k][n]
__global__ void w_prep(const float* __restrict__ W, int K, int N, int KPp, int NPp,
                       u16* __restrict__ Thi, u16* __restrict__ Tlo)
{
    int blk = blockIdx.x;           // l*NPp + n
    int l = blk / NPp, n = blk % NPp;
    int k = threadIdx.x;
    if (k >= KPp) return;
    float v = (n < N && k < K) ? W[((size_t)l * K + k) * N + n] : 0.f;
    u16 hi, lo; split2(v, hi, lo);
    size_t o = ((size_t)l * NPp + n) * KPp + k;
    Thi[o] = hi; Tlo[o] = lo;
}

// ---------------- fused aggregate + GIN update -> split-bf16 A1 ----------------
__global__ __launch_bounds__(320) void agg_kernel(const float* __restrict__ h,
    const int* __restrict__ rec, const int* __restrict__ rowptr,
    const float* __restrict__ combo_l, const float* __restrict__ eps, int l,
    u16* __restrict__ zhi, u16* __restrict__ zlo)
{
    int n = blockIdx.x;
    int t = threadIdx.x;
    if (t >= DD) {
        if (t < KP1) { zhi[(size_t)n * KP1 + t] = 0; zlo[(size_t)n * KP1 + t] = 0; }
        return;
    }
    int beg = rowptr[n], end = rowptr[n + 1];
    float acc = 0.f;
    for (int i = beg; i < end; ++i) {
        int r = rec[i];
        int s = r & 0xFFFFF;
        int code = ((unsigned)r) >> 20;
        float v = h[(size_t)s * DD + t] + combo_l[(size_t)code * DD + t];
        acc += fmaxf(v, 0.f);
    }
    float se = 1.0f + eps[l];
    float z = fmaf(se, h[(size_t)n * DD + t], acc);
    u16 hi, lo; split2(z, hi, lo);
    zhi[(size_t)n * KP1 + t] = hi;
    zlo[(size_t)n * KP1 + t] = lo;
}

// ---------------- bf16-split MFMA GEMM: C[M,N] = (Ahi+Alo)@(Bhi+Blo)^T + bias ----
// A: [Mpad][kpa] row-major bf16 (hi/lo). B: [Npad][kpa] row-major bf16 (= W^T).
// 128x128 tile, 4 waves (2x2 of 64x64), BK=32, mfma_f32_16x16x32_bf16 x3 passes.
// MODE 0: Cf fp32 [M][N] + bias.  MODE 1: split bf16 out [M][kpo] + bias, zero-pad cols N..kpo.
template <int MODE>
__global__ __launch_bounds__(256) void gemm_mfma(
    const u16* __restrict__ Ahi, const u16* __restrict__ Alo, int kpa,
    const u16* __restrict__ Bhi, const u16* __restrict__ Blo,
    const float* __restrict__ bias, int M, int N, int ksteps,
    float* __restrict__ Cf, u16* __restrict__ Ohi, u16* __restrict__ Olo, int kpo)
{
    __shared__ __align__(16) u16 Ah[4][128][8];
    __shared__ __align__(16) u16 Al[4][128][8];
    __shared__ __align__(16) u16 Bh[4][128][8];
    __shared__ __align__(16) u16 Bl[4][128][8];

    const int t = threadIdx.x;
    const int lane = t & 63, w = t >> 6;
    const int l15 = lane & 15, l4 = lane >> 4;
    const int wr = w >> 1, wc = w & 1;
    const int row0 = blockIdx.x * 128;
    const int col0 = blockIdx.y * 128;

    // staging sources: wave w stages k-group w (cols w*8..w*8+7 of each 32-wide K-step)
    const u16* gAh0 = Ahi + (size_t)(row0 + lane) * kpa + w * 8;
    const u16* gAh1 = Ahi + (size_t)(row0 + 64 + lane) * kpa + w * 8;
    const u16* gAl0 = Alo + (size_t)(row0 + lane) * kpa + w * 8;
    const u16* gAl1 = Alo + (size_t)(row0 + 64 + lane) * kpa + w * 8;
    const u16* gBh0 = Bhi + (size_t)(col0 + lane) * kpa + w * 8;
    const u16* gBh1 = Bhi + (size_t)(col0 + 64 + lane) * kpa + w * 8;
    const u16* gBl0 = Blo + (size_t)(col0 + lane) * kpa + w * 8;
    const u16* gBl1 = Blo + (size_t)(col0 + 64 + lane) * kpa + w * 8;

    f32x4 acc[4][4];
#pragma unroll
    for (int i = 0; i < 4; ++i)
#pragma unroll
        for (int j = 0; j < 4; ++j) acc[i][j] = (f32x4){0.f, 0.f, 0.f, 0.f};

    for (int ks = 0; ks < ksteps; ++ks) {
        g2l16(gAh0, &Ah[w][0][0]);
        g2l16(gAh1, &Ah[w][64][0]);
        g2l16(gAl0, &Al[w][0][0]);
        g2l16(gAl1, &Al[w][64][0]);
        g2l16(gBh0, &Bh[w][0][0]);
        g2l16(gBh1, &Bh[w][64][0]);
        g2l16(gBl0, &Bl[w][0][0]);
        g2l16(gBl1, &Bl[w][64][0]);
        gAh0 += 32; gAh1 += 32; gAl0 += 32; gAl1 += 32;
        gBh0 += 32; gBh1 += 32; gBl0 += 32; gBl1 += 32;
        __syncthreads();

        bf16x8 a_h[4], a_l[4], b_h[4], b_l[4];
#pragma unroll
        for (int i = 0; i < 4; ++i) {
            int r = wr * 64 + i * 16 + l15;
            a_h[i] = *(const bf16x8*)Ah[l4][r];
            a_l[i] = *(const bf16x8*)Al[l4][r];
            int c = wc * 64 + i * 16 + l15;
            b_h[i] = *(const bf16x8*)Bh[l4][c];
            b_l[i] = *(const bf16x8*)Bl[l4][c];
        }
#pragma unroll
        for (int mi = 0; mi < 4; ++mi)
#pragma unroll
            for (int ni = 0; ni < 4; ++ni) {
                acc[mi][ni] = __builtin_amdgcn_mfma_f32_16x16x32_bf16(a_h[mi], b_h[ni], acc[mi][ni], 0, 0, 0);
                acc[mi][ni] = __builtin_amdgcn_mfma_f32_16x16x32_bf16(a_h[mi], b_l[ni], acc[mi][ni], 0, 0, 0);
                acc[mi][ni] = __builtin_amdgcn_mfma_f32_16x16x32_bf16(a_l[mi], b_h[ni], acc[mi][ni], 0, 0, 0);
            }
        __syncthreads();
    }

#pragma unroll
    for (int mi = 0; mi < 4; ++mi) {
#pragma unroll
        for (int ni = 0; ni < 4; ++ni) {
#pragma unroll
            for (int r = 0; r < 4; ++r) {
                int gr = row0 + wr * 64 + mi * 16 + l4 * 4 + r;
                int gc = col0 + wc * 64 + ni * 16 + l15;
                if (gr >= M) continue;
                if (MODE == 0) {
                    if (gc < N) Cf[(size_t)gr * N + gc] = acc[mi][ni][r] + bias[gc];
                } else {
                    if (gc < N) {
                        u16 hi, lo;
                        split2(acc[mi][ni][r] + bias[gc], hi, lo);
                        size_t o = (size_t)gr * kpo + gc;
                        Ohi[o] = hi; Olo[o] = lo;
                    } else if (gc < kpo) {
                        size_t o = (size_t)gr * kpo + gc;
                        Ohi[o] = 0; Olo[o] = 0;
                    }
                }
            }
        }
    }
}

// ---------------- column stats over split-bf16 matrix ----------------
__global__ __launch_bounds__(256) void colstats_bf(const u16* __restrict__ hi,
    const u16* __restrict__ lo, int rows, int cols, int stride,
    float* __restrict__ cs, float* __restrict__ csq, int rpb)
{
    int r0 = blockIdx.x * rpb;
    int r1 = min(r0 + rpb, rows);
    int t = threadIdx.x;
    float s[3] = {0.f, 0.f, 0.f}, q[3] = {0.f, 0.f, 0.f};
    for (int r = r0; r < r1; ++r) {
        const u16* rh = hi + (size_t)r * stride;
        const u16* rl = lo + (size_t)r * stride;
#pragma unroll
        for (int ci = 0; ci < 3; ++ci) {
            int c = t + ci * 256;
            if (c < cols) { float v = bf2f(rh[c]) + bf2f(rl[c]); s[ci] += v; q[ci] += v * v; }
        }
    }
#pragma unroll
    for (int ci = 0; ci < 3; ++ci) {
        int c = t + ci * 256;
        if (c < cols) { atomicAdd(&cs[c], s[ci]); atomicAdd(&csq[c], q[ci]); }
    }
}

// ---------------- column stats fp32 ----------------
__global__ __launch_bounds__(256) void colstats(const float* __restrict__ Mx,
    int rows, int cols, float* __restrict__ cs, float* __restrict__ csq, int rpb)
{
    int r0 = blockIdx.x * rpb;
    int r1 = min(r0 + rpb, rows);
    int t = threadIdx.x;
    float s[3] = {0.f, 0.f, 0.f}, q[3] = {0.f, 0.f, 0.f};
    for (int r = r0; r < r1; ++r) {
        const float* row = Mx + (size_t)r * cols;
#pragma unroll
        for (int ci = 0; ci < 3; ++ci) {
            int c = t + ci * 256;
            if (c < cols) { float v = row[c]; s[ci] += v; q[ci] += v * v; }
        }
    }
#pragma unroll
    for (int ci = 0; ci < 3; ++ci) {
        int c = t + ci * 256;
        if (c < cols) { atomicAdd(&cs[c], s[ci]); atomicAdd(&csq[c], q[ci]); }
    }
}

// ---------------- finalize BN ----------------
__global__ void bn_fin(const float* __restrict__ cs, const float* __restrict__ csq,
                       const float* __restrict__ g, const float* __restrict__ be,
                       float* __restrict__ scale, float* __restrict__ shift,
                       int cols, float invn)
{
    int c = blockIdx.x * blockDim.x + threadIdx.x;
    if (c >= cols) return;
    float mu = cs[c] * invn;
    float var = csq[c] * invn - mu * mu;
    float rs = rsqrtf(var + 1e-5f);
    float sc = rs * g[c];
    scale[c] = sc;
    shift[c] = be[c] - mu * sc;
}

// ---------------- in-place BN1 + ReLU on split-bf16 Z1 ----------------
__global__ void bn1_split(u16* __restrict__ hi, u16* __restrict__ lo,
    const float* __restrict__ sc, const float* __restrict__ sh, int rows)
{
    int i = blockIdx.x * blockDim.x + threadIdx.x;
    int stride = gridDim.x * blockDim.x;
    int total = rows * 75;                    // 75 chunks of 8 cols cover 600; pad chunk skipped
    for (; i < total; i += stride) {
        int r = i / 75, cq = i - r * 75;
        int c0 = cq * 8;
        size_t o = (size_t)r * KP2 + c0;
        uint4 vh = *(const uint4*)(hi + o);
        uint4 vl = *(const uint4*)(lo + o);
        const u16* ph = (const u16*)&vh;
        const u16* pl = (const u16*)&vl;
        u16 oh[8], ol[8];
#pragma unroll
        for (int j = 0; j < 8; ++j) {
            float v = bf2f(ph[j]) + bf2f(pl[j]);
            v = fmaxf(fmaf(v, sc[c0 + j], sh[c0 + j]), 0.f);
            split2(v, oh[j], ol[j]);
        }
        *(uint4*)(hi + o) = *(const uint4*)oh;
        *(uint4*)(lo + o) = *(const uint4*)ol;
    }
}

// ---------------- apply BN2 (+optional ReLU): h = Z*scale[c]+shift[c] ----------------
__global__ void bn_apply(const float* __restrict__ Z, float* __restrict__ H,
                         const float* __restrict__ scale, const float* __restrict__ shift,
                         int n4, int relu)
{
    int i = blockIdx.x * blockDim.x + threadIdx.x;
    int stride = gridDim.x * blockDim.x;
    for (; i < n4; i += stride) {
        float4 v = ((const float4*)Z)[i];
        int c0 = (i * 4) % DD;
        float4 o;
        o.x = fmaf(v.x, scale[c0 + 0], shift[c0 + 0]);
        o.y = fmaf(v.y, scale[c0 + 1], shift[c0 + 1]);
        o.z = fmaf(v.z, scale[c0 + 2], shift[c0 + 2]);
        o.w = fmaf(v.w, scale[c0 + 3], shift[c0 + 3]);
        if (relu) {
            o.x = fmaxf(o.x, 0.f); o.y = fmaxf(o.y, 0.f);
            o.z = fmaxf(o.z, 0.f); o.w = fmaxf(o.w, 0.f);
        }
        ((float4*)H)[i] = o;
    }
}

// ---------------- global_add_pool ----------------
__global__ __launch_bounds__(320) void pool_kernel(const float* __restrict__ h,
    const int* __restrict__ batch, int N, float* __restrict__ hg)
{
    int g = blockIdx.x;
    int lo = 0, hi = N;
    while (lo < hi) { int mid = (lo + hi) >> 1; if (batch[mid] < g) lo = mid + 1; else hi = mid; }
    int start = lo;
    hi = N;
    while (lo < hi) { int mid = (lo + hi) >> 1; if (batch[mid] <= g) lo = mid + 1; else hi = mid; }
    int end = lo;
    int d = threadIdx.x;
    if (d >= DD) return;
    float s = 0.f;
    for (int i = start; i < end; ++i) s += h[(size_t)i * DD + d];
    hg[(size_t)g * DD + d] = s;
}

// ---------------- GroupNorm + head ----------------
__global__ __launch_bounds__(256) void head_kernel(const float* __restrict__ hg,
    const float* __restrict__ w, const float* __restrict__ b, float* __restrict__ out)
{
    __shared__ float red[256];
    int g = blockIdx.x, t = threadIdx.x;
    const float* row = hg + (size_t)g * DD;
    float v0 = (t < DD) ? row[t] : 0.f;
    float v1 = (t + 256 < DD) ? row[t + 256] : 0.f;

    red[t] = v0 + v1;
    __syncthreads();
    for (int o = 128; o > 0; o >>= 1) { if (t < o) red[t] += red[t + o]; __syncthreads(); }
    float mean = red[0] * (1.f / (float)DD);
    __syncthreads();

    red[t] = v0 * v0 + v1 * v1;
    __syncthreads();
    for (int o = 128; o > 0; o >>= 1) { if (t < o) red[t] += red[t + o]; __syncthreads(); }
    float var = red[0] * (1.f / (float)DD) - mean * mean;
    float rs = rsqrtf(var + 1e-5f);
    __syncthreads();

    float d0 = (t < DD) ? (v0 - mean) * rs * w[t] : 0.f;
    float d1 = (t + 256 < DD) ? (v1 - mean) * rs * w[t + 256] : 0.f;
    red[t] = d0 + d1;
    __syncthreads();
    for (int o = 128; o > 0; o >>= 1) { if (t < o) red[t] += red[t + o]; __syncthreads(); }
    if (t == 0) out[g] = red[0] + b[0];
}

extern "C" void kernel_launch(void* const* d_in, const int* in_sizes, int n_in,
                              void* d_out, int out_size, void* d_ws, size_t ws_size,
                              hipStream_t stream)
{
    (void)n_in; (void)out_size; (void)ws_size;
    const int*   x         = (const int*)  d_in[0];
    const int*   edge_idx  = (const int*)  d_in[1];
    const int*   edge_attr = (const int*)  d_in[2];
    const int*   batch     = (const int*)  d_in[3];
    const float* atom_emb  = (const float*)d_in[4];
    const float* bond_emb  = (const float*)d_in[5];
    const float* eps       = (const float*)d_in[6];
    const float* W1        = (const float*)d_in[7];
    const float* b1        = (const float*)d_in[8];
    const float* g1        = (const float*)d_in[9];
    const float* be1       = (const float*)d_in[10];
    const float* W2        = (const float*)d_in[11];
    const float* b2        = (const float*)d_in[12];
    const float* g2        = (const float*)d_in[13];
    const float* be2       = (const float*)d_in[14];
    const float* head_w    = (const float*)d_in[15];
    const float* head_b    = (const float*)d_in[16];

    const int NN = in_sizes[3];          // nodes (20000)
    const int E  = in_sizes[1] / 2;      // edges (320000)
    const int gm = (NN + 127) / 128;     // 157 M-blocks
    const int mpad = gm * 128;           // 20096

    char* p = (char*)d_ws;
    auto alloc = [&](size_t bytes) { char* r = p; p += (bytes + 255) & ~(size_t)255; return r; };

    float* h    = (float*)alloc((size_t)NN * DD * 4);
    u16* A1hi   = (u16*)  alloc((size_t)mpad * KP1 * 2);
    u16* A1lo   = (u16*)  alloc((size_t)mpad * KP1 * 2);
    float* zb2  = (float*)A1hi;   // alias: zb2 (N*300 f32 = 24MB) reuses A1hi+A1lo (25.7MB); safe by stream order
    u16* Z1hi   = (u16*)  alloc((size_t)mpad * KP2 * 2);
    u16* Z1lo   = (u16*)  alloc((size_t)mpad * KP2 * 2);
    u16* W1Thi  = (u16*)  alloc((size_t)LL * NP1 * KP1 * 2);
    u16* W1Tlo  = (u16*)  alloc((size_t)LL * NP1 * KP1 * 2);
    u16* W2Thi  = (u16*)  alloc((size_t)LL * NP2 * KP2 * 2);
    u16* W2Tlo  = (u16*)  alloc((size_t)LL * NP2 * KP2 * 2);
    float* combo= (float*)alloc((size_t)LL * 512 * DD * 4);
    float* hg   = (float*)alloc((size_t)NGG * DD * 4);
    float* cs   = (float*)alloc(HH * 4);
    float* csq  = (float*)alloc(HH * 4);
    float* sc1  = (float*)alloc(HH * 4);
    float* sh1  = (float*)alloc(HH * 4);
    float* sc2  = (float*)alloc(DD * 4);
    float* sh2  = (float*)alloc(DD * 4);
    int* cnt    = (int*)  alloc((size_t)NN * 4);
    int* cursor = (int*)  alloc((size_t)NN * 4);
    int* rowptr = (int*)  alloc((size_t)(NN + 1) * 4);
    int* rec    = (int*)  alloc((size_t)E * 4);

    const int* src = edge_idx;
    const int* dst = edge_idx + E;

    // ---- per-call setup: CSR, combo tables, weight transpose/split, atom enc ----
    hipMemsetAsync(cnt, 0, (size_t)NN * sizeof(int), stream);
    hipMemsetAsync(cursor, 0, (size_t)NN * sizeof(int), stream);
    csr_count<<<512, 256, 0, stream>>>(dst, E, cnt);
    scan_kernel<<<1, 1024, 0, stream>>>(cnt, rowptr, NN);
    csr_fill<<<512, 256, 0, stream>>>(src, dst, edge_attr, rowptr, cursor, rec, E);
    combo_build<<<LL * 512, 320, 0, stream>>>(bond_emb, combo);
    w_prep<<<LL * NP1, KP1, 0, stream>>>(W1, DD, HH, KP1, NP1, W1Thi, W1Tlo);
    w_prep<<<LL * NP2, KP2, 0, stream>>>(W2, HH, DD, KP2, NP2, W2Thi, W2Tlo);
    atom_kernel<<<NN, 320, 0, stream>>>(x, atom_emb, h, NN);

    for (int l = 0; l < LL; ++l) {
        agg_kernel<<<NN, 320, 0, stream>>>(h, rec, rowptr,
            combo + (size_t)l * 512 * DD, eps, l, A1hi, A1lo);

        gemm_mfma<1><<<dim3(gm, NP1 / 128), 256, 0, stream>>>(
            A1hi, A1lo, KP1,
            W1Thi + (size_t)l * NP1 * KP1, W1Tlo + (size_t)l * NP1 * KP1,
            b1 + (size_t)l * HH, NN, HH, KP1 / 32,
            nullptr, Z1hi, Z1lo, KP2);

        hipMemsetAsync(cs, 0, HH * sizeof(float), stream);
        hipMemsetAsync(csq, 0, HH * sizeof(float), stream);
        colstats_bf<<<(NN + 63) / 64, 256, 0, stream>>>(Z1hi, Z1lo, NN, HH, KP2, cs, csq, 64);
        bn_fin<<<(HH + 255) / 256, 256, 0, stream>>>(cs, csq, g1 + (size_t)l * HH,
            be1 + (size_t)l * HH, sc1, sh1, HH, 1.f / (float)NN);

        bn1_split<<<2048, 256, 0, stream>>>(Z1hi, Z1lo, sc1, sh1, NN);

        gemm_mfma<0><<<dim3(gm, NP2 / 128), 256, 0, stream>>>(
            Z1hi, Z1lo, KP2,
            W2Thi + (size_t)l * NP2 * KP2, W2Tlo + (size_t)l * NP2 * KP2,
            b2 + (size_t)l * DD, NN, DD, KP2 / 32,
            zb2, nullptr, nullptr, 0);

        hipMemsetAsync(cs, 0, DD * sizeof(float), stream);
        hipMemsetAsync(csq, 0, DD * sizeof(float), stream);
        colstats<<<(NN + 63) / 64, 256, 0, stream>>>(zb2, NN, DD, cs, csq, 64);
        bn_fin<<<(DD + 255) / 256, 256, 0, stream>>>(cs, csq, g2 + (size_t)l * DD,
            be2 + (size_t)l * DD, sc2, sh2, DD, 1.f / (float)NN);

        bn_apply<<<1024, 256, 0, stream>>>(zb2, h, sc2, sh2, NN * DD / 4, (l < LL - 1) ? 1 : 0);
    }

    pool_kernel<<<NGG, 320, 0, stream>>>(h, batch, NN, hg);
    head_kernel<<<NGG, 256, 0, stream>>>(hg, head_w, head_b, (float*)d_out);
}

// Round 4
// 1785.898 us; speedup vs baseline: 2.1828x; 1.1322x over previous
//
#include <hip/hip_runtime.h>
#include <cstddef>
#include <cstdint>

#define DD 300
#define HH 600
#define LL 5
#define NGG 512
#define KP1 320     // padded K for GEMM1 (D=300 -> 10 K-steps of 32)
#define KP2 608     // padded K for GEMM2 (H=600 -> 19 K-steps of 32)
#define NP1 640     // padded N-rows of W1^T (600 -> 5 col-blocks of 128)
#define NP2 384     // padded N-rows of W2^T (300 -> 3 col-blocks of 128)

typedef unsigned short u16;
typedef short bf16x8 __attribute__((ext_vector_type(8)));
typedef float f32x4 __attribute__((ext_vector_type(4)));

__device__ __forceinline__ float bf2f(u16 h) { return __uint_as_float(((unsigned)h) << 16); }

// RNE split: v = hi + lo (two bf16, ~16 mantissa bits total)
__device__ __forceinline__ void split2(float v, u16& hi, u16& lo)
{
    unsigned u = __float_as_uint(v);
    unsigned r = (u + 0x7FFFu + ((u >> 16) & 1u)) >> 16;
    hi = (u16)r;
    float res = v - __uint_as_float(r << 16);
    unsigned u2 = __float_as_uint(res);
    lo = (u16)((u2 + 0x7FFFu + ((u2 >> 16) & 1u)) >> 16);
}

__device__ __forceinline__ void g2l16(const void* g, void* l)
{
    __builtin_amdgcn_global_load_lds(
        (const __attribute__((address_space(1))) void*)g,
        (__attribute__((address_space(3))) void*)l, 16, 0, 0);
}

// ---------------- Atom encoder ----------------
__global__ __launch_bounds__(320) void atom_kernel(const int* __restrict__ x,
    const float* __restrict__ emb, float* __restrict__ h, int N)
{
    __shared__ int xi[9];
    int n = blockIdx.x;
    int t = threadIdx.x;
    if (t < 9) xi[t] = x[n * 9 + t] + t * 64;
    __syncthreads();
    if (t >= DD) return;
    float s = 0.f;
#pragma unroll
    for (int f = 0; f < 9; ++f) s += emb[(size_t)xi[f] * DD + t];
    h[(size_t)n * DD + t] = s;
}

// ---------------- CSR build ----------------
__global__ void csr_count(const int* __restrict__ dst, int E, int* __restrict__ cnt)
{
    int i = blockIdx.x * blockDim.x + threadIdx.x;
    int stride = gridDim.x * blockDim.x;
    for (; i < E; i += stride) atomicAdd(&cnt[dst[i]], 1);
}

__global__ __launch_bounds__(1024) void scan_kernel(const int* __restrict__ cnt,
    int* __restrict__ rowptr, int n)
{
    __shared__ int buf[1024];
    int t = threadIdx.x;
    int carry = 0;
    for (int base = 0; base < n; base += 1024) {
        int v = (base + t < n) ? cnt[base + t] : 0;
        buf[t] = v;
        __syncthreads();
        for (int off = 1; off < 1024; off <<= 1) {
            int x = (t >= off) ? buf[t - off] : 0;
            __syncthreads();
            buf[t] += x;
            __syncthreads();
        }
        if (base + t < n) rowptr[base + t] = buf[t] - v + carry;
        int total = buf[1023];
        __syncthreads();
        carry += total;
    }
    if (t == 0) rowptr[n] = carry;
}

__global__ void csr_fill(const int* __restrict__ src, const int* __restrict__ dst,
    const int* __restrict__ ea, const int* __restrict__ rowptr,
    int* __restrict__ cursor, int* __restrict__ rec, int E)
{
    int i = blockIdx.x * blockDim.x + threadIdx.x;
    int stride = gridDim.x * blockDim.x;
    for (; i < E; i += stride) {
        int d = dst[i];
        int pos = rowptr[d] + atomicAdd(&cursor[d], 1);
        int code = ea[i * 3] | (ea[i * 3 + 1] << 3) | (ea[i * 3 + 2] << 6);
        rec[pos] = src[i] | (code << 20);
    }
}

// ---------------- per-layer bond-code combo table ----------------
__global__ __launch_bounds__(320) void combo_build(const float* __restrict__ bond,
    float* __restrict__ combo)
{
    int blk = blockIdx.x;           // l*512 + code
    int l = blk >> 9, code = blk & 511;
    int t = threadIdx.x;
    if (t >= DD) return;
    const float* bl = bond + (size_t)l * 24 * DD;
    combo[(size_t)blk * DD + t] = bl[(size_t)(code & 7) * DD + t]
                                + bl[(size_t)(8 + ((code >> 3) & 7)) * DD + t]
                                + bl[(size_t)(16 + (code >> 6)) * DD + t];
}

// ---------------- LDS-tiled weight transpose + bf16-split, zero-padded ----------------
// W [L][K][N] fp32 -> T [L][NPp][KPp] bf16 hi/lo with T[l][n][k] = W[l][k][n]
__global__ __launch_bounds__(256) void w_prep_t(const float* __restrict__ W,
    int K, int N, int KPp, int NPp, int ktiles,
    u16* __restrict__ Thi, u16* __restrict__ Tlo)
{
    __shared__ float tile[64][65];
    int ntiles = NPp >> 6;
    int blk = blockIdx.x;            // l*ktiles*ntiles + kt*ntiles + nt
    int l = blk / (ktiles * ntiles);
    int rem = blk % (ktiles * ntiles);
    int k0 = (rem / ntiles) << 6;
    int n0 = (rem % ntiles) << 6;
    int tn = threadIdx.x & 63;
    int tg = threadIdx.x >> 6;       // 0..3
    const float* Wl = W + (size_t)l * K * N;
    for (int kk = tg; kk < 64; kk += 4) {
        int gk = k0 + kk, gn = n0 + tn;
        tile[kk][tn] = (gk < K && gn < N) ? Wl[(size_t)gk * N + gn] : 0.f;
    }
    __syncthreads();
    for (int nn = tg; nn < 64; nn += 4) {
        int gn = n0 + nn, gk = k0 + tn;
        if (gk < KPp) {
            u16 hi, lo; split2(tile[tn][nn], hi, lo);
            size_t o = ((size_t)l * NPp + gn) * KPp + gk;
            Thi[o] = hi; Tlo[o] = lo;
        }
    }
}

// ---------------- fused aggregate + GIN update -> split-bf16 A1 (unroll-4 MLP) ----------------
__global__ __launch_bounds__(320) void agg_kernel(const float* __restrict__ h,
    const int* __restrict__ rec, const int* __restrict__ rowptr,
    const float* __restrict__ combo_l, const float* __restrict__ eps, int l,
    u16* __restrict__ zhi, u16* __restrict__ zlo)
{
    int n = blockIdx.x;
    int t = threadIdx.x;
    if (t >= DD) {
        if (t < KP1) { zhi[(size_t)n * KP1 + t] = 0; zlo[(size_t)n * KP1 + t] = 0; }
        return;
    }
    int beg = rowptr[n], end = rowptr[n + 1];
    float acc = 0.f;
    int i = beg;
    for (; i + 4 <= end; i += 4) {
        int r0 = rec[i], r1 = rec[i + 1], r2 = rec[i + 2], r3 = rec[i + 3];
        const float* p0 = h + (size_t)(r0 & 0xFFFFF) * DD;
        const float* p1 = h + (size_t)(r1 & 0xFFFFF) * DD;
        const float* p2 = h + (size_t)(r2 & 0xFFFFF) * DD;
        const float* p3 = h + (size_t)(r3 & 0xFFFFF) * DD;
        const float* q0 = combo_l + (size_t)(((unsigned)r0) >> 20) * DD;
        const float* q1 = combo_l + (size_t)(((unsigned)r1) >> 20) * DD;
        const float* q2 = combo_l + (size_t)(((unsigned)r2) >> 20) * DD;
        const float* q3 = combo_l + (size_t)(((unsigned)r3) >> 20) * DD;
        float h0 = p0[t], h1 = p1[t], h2 = p2[t], h3 = p3[t];
        float c0 = q0[t], c1 = q1[t], c2 = q2[t], c3 = q3[t];
        acc += fmaxf(h0 + c0, 0.f) + fmaxf(h1 + c1, 0.f)
             + fmaxf(h2 + c2, 0.f) + fmaxf(h3 + c3, 0.f);
    }
    for (; i < end; ++i) {
        int r = rec[i];
        float v = h[(size_t)(r & 0xFFFFF) * DD + t]
                + combo_l[(size_t)(((unsigned)r) >> 20) * DD + t];
        acc += fmaxf(v, 0.f);
    }
    float se = 1.0f + eps[l];
    float z = fmaf(se, h[(size_t)n * DD + t], acc);
    u16 hi, lo; split2(z, hi, lo);
    zhi[(size_t)n * KP1 + t] = hi;
    zlo[(size_t)n * KP1 + t] = lo;
}

// ---------------- bf16-split MFMA GEMM (3-pass): C = (Ahi+Alo)@(Bhi+Blo)^T + bias ----
template <int MODE>
__global__ __launch_bounds__(256) void gemm_mfma(
    const u16* __restrict__ Ahi, const u16* __restrict__ Alo, int kpa,
    const u16* __restrict__ Bhi, const u16* __restrict__ Blo,
    const float* __restrict__ bias, int M, int N, int ksteps,
    float* __restrict__ Cf, u16* __restrict__ Ohi, u16* __restrict__ Olo, int kpo)
{
    __shared__ __align__(16) u16 Ah[4][128][8];
    __shared__ __align__(16) u16 Al[4][128][8];
    __shared__ __align__(16) u16 Bh[4][128][8];
    __shared__ __align__(16) u16 Bl[4][128][8];

    const int t = threadIdx.x;
    const int lane = t & 63, w = t >> 6;
    const int l15 = lane & 15, l4 = lane >> 4;
    const int wr = w >> 1, wc = w & 1;
    const int row0 = blockIdx.x * 128;
    const int col0 = blockIdx.y * 128;

    const u16* gAh0 = Ahi + (size_t)(row0 + lane) * kpa + w * 8;
    const u16* gAh1 = Ahi + (size_t)(row0 + 64 + lane) * kpa + w * 8;
    const u16* gAl0 = Alo + (size_t)(row0 + lane) * kpa + w * 8;
    const u16* gAl1 = Alo + (size_t)(row0 + 64 + lane) * kpa + w * 8;
    const u16* gBh0 = Bhi + (size_t)(col0 + lane) * kpa + w * 8;
    const u16* gBh1 = Bhi + (size_t)(col0 + 64 + lane) * kpa + w * 8;
    const u16* gBl0 = Blo + (size_t)(col0 + lane) * kpa + w * 8;
    const u16* gBl1 = Blo + (size_t)(col0 + 64 + lane) * kpa + w * 8;

    f32x4 acc[4][4];
#pragma unroll
    for (int i = 0; i < 4; ++i)
#pragma unroll
        for (int j = 0; j < 4; ++j) acc[i][j] = (f32x4){0.f, 0.f, 0.f, 0.f};

    for (int ks = 0; ks < ksteps; ++ks) {
        g2l16(gAh0, &Ah[w][0][0]);
        g2l16(gAh1, &Ah[w][64][0]);
        g2l16(gAl0, &Al[w][0][0]);
        g2l16(gAl1, &Al[w][64][0]);
        g2l16(gBh0, &Bh[w][0][0]);
        g2l16(gBh1, &Bh[w][64][0]);
        g2l16(gBl0, &Bl[w][0][0]);
        g2l16(gBl1, &Bl[w][64][0]);
        gAh0 += 32; gAh1 += 32; gAl0 += 32; gAl1 += 32;
        gBh0 += 32; gBh1 += 32; gBl0 += 32; gBl1 += 32;
        __syncthreads();

        bf16x8 a_h[4], a_l[4], b_h[4], b_l[4];
#pragma unroll
        for (int i = 0; i < 4; ++i) {
            int r = wr * 64 + i * 16 + l15;
            a_h[i] = *(const bf16x8*)Ah[l4][r];
            a_l[i] = *(const bf16x8*)Al[l4][r];
            int c = wc * 64 + i * 16 + l15;
            b_h[i] = *(const bf16x8*)Bh[l4][c];
            b_l[i] = *(const bf16x8*)Bl[l4][c];
        }
#pragma unroll
        for (int mi = 0; mi < 4; ++mi)
#pragma unroll
            for (int ni = 0; ni < 4; ++ni) {
                acc[mi][ni] = __builtin_amdgcn_mfma_f32_16x16x32_bf16(a_h[mi], b_h[ni], acc[mi][ni], 0, 0, 0);
                acc[mi][ni] = __builtin_amdgcn_mfma_f32_16x16x32_bf16(a_h[mi], b_l[ni], acc[mi][ni], 0, 0, 0);
                acc[mi][ni] = __builtin_amdgcn_mfma_f32_16x16x32_bf16(a_l[mi], b_h[ni], acc[mi][ni], 0, 0, 0);
            }
        __syncthreads();
    }

#pragma unroll
    for (int mi = 0; mi < 4; ++mi) {
#pragma unroll
        for (int ni = 0; ni < 4; ++ni) {
#pragma unroll
            for (int r = 0; r < 4; ++r) {
                int gr = row0 + wr * 64 + mi * 16 + l4 * 4 + r;
                int gc = col0 + wc * 64 + ni * 16 + l15;
                if (gr >= M) continue;
                if (MODE == 0) {
                    if (gc < N) Cf[(size_t)gr * N + gc] = acc[mi][ni][r] + bias[gc];
                } else {
                    if (gc < N) {
                        u16 hi, lo;
                        split2(acc[mi][ni][r] + bias[gc], hi, lo);
                        size_t o = (size_t)gr * kpo + gc;
                        Ohi[o] = hi; Olo[o] = lo;
                    } else if (gc < kpo) {
                        size_t o = (size_t)gr * kpo + gc;
                        Ohi[o] = 0; Olo[o] = 0;
                    }
                }
            }
        }
    }
}

// ---------------- column stats over split-bf16 matrix ----------------
__global__ __launch_bounds__(256) void colstats_bf(const u16* __restrict__ hi,
    const u16* __restrict__ lo, int rows, int cols, int stride,
    float* __restrict__ cs, float* __restrict__ csq, int rpb)
{
    int r0 = blockIdx.x * rpb;
    int r1 = min(r0 + rpb, rows);
    int t = threadIdx.x;
    float s[3] = {0.f, 0.f, 0.f}, q[3] = {0.f, 0.f, 0.f};
    for (int r = r0; r < r1; ++r) {
        const u16* rh = hi + (size_t)r * stride;
        const u16* rl = lo + (size_t)r * stride;
#pragma unroll
        for (int ci = 0; ci < 3; ++ci) {
            int c = t + ci * 256;
            if (c < cols) { float v = bf2f(rh[c]) + bf2f(rl[c]); s[ci] += v; q[ci] += v * v; }
        }
    }
#pragma unroll
    for (int ci = 0; ci < 3; ++ci) {
        int c = t + ci * 256;
        if (c < cols) { atomicAdd(&cs[c], s[ci]); atomicAdd(&csq[c], q[ci]); }
    }
}

// ---------------- column stats fp32 ----------------
__global__ __launch_bounds__(256) void colstats(const float* __restrict__ Mx,
    int rows, int cols, float* __restrict__ cs, float* __restrict__ csq, int rpb)
{
    int r0 = blockIdx.x * rpb;
    int r1 = min(r0 + rpb, rows);
    int t = threadIdx.x;
    float s[3] = {0.f, 0.f, 0.f}, q[3] = {0.f, 0.f, 0.f};
    for (int r = r0; r < r1; ++r) {
        const float* row = Mx + (size_t)r * cols;
#pragma unroll
        for (int ci = 0; ci < 3; ++ci) {
            int c = t + ci * 256;
            if (c < cols) { float v = row[c]; s[ci] += v; q[ci] += v * v; }
        }
    }
#pragma unroll
    for (int ci = 0; ci < 3; ++ci) {
        int c = t + ci * 256;
        if (c < cols) { atomicAdd(&cs[c], s[ci]); atomicAdd(&csq[c], q[ci]); }
    }
}

// ---------------- finalize BN; self-clean stats buffers for next use ----------------
__global__ void bn_fin(float* __restrict__ cs, float* __restrict__ csq,
                       const float* __restrict__ g, const float* __restrict__ be,
                       float* __restrict__ scale, float* __restrict__ shift,
                       int cols, float invn)
{
    int c = blockIdx.x * blockDim.x + threadIdx.x;
    if (c >= cols) return;
    float mu = cs[c] * invn;
    float var = csq[c] * invn - mu * mu;
    float rs = rsqrtf(var + 1e-5f);
    float sc = rs * g[c];
    scale[c] = sc;
    shift[c] = be[c] - mu * sc;
    cs[c] = 0.f;
    csq[c] = 0.f;
}

// ---------------- in-place BN1 + ReLU on split-bf16 Z1 ----------------
__global__ void bn1_split(u16* __restrict__ hi, u16* __restrict__ lo,
    const float* __restrict__ sc, const float* __restrict__ sh, int rows)
{
    int i = blockIdx.x * blockDim.x + threadIdx.x;
    int stride = gridDim.x * blockDim.x;
    int total = rows * 75;                    // 75 chunks of 8 cols cover 600
    for (; i < total; i += stride) {
        int r = i / 75, cq = i - r * 75;
        int c0 = cq * 8;
        size_t o = (size_t)r * KP2 + c0;
        uint4 vh = *(const uint4*)(hi + o);
        uint4 vl = *(const uint4*)(lo + o);
        const u16* ph = (const u16*)&vh;
        const u16* pl = (const u16*)&vl;
        u16 oh[8], ol[8];
#pragma unroll
        for (int j = 0; j < 8; ++j) {
            float v = bf2f(ph[j]) + bf2f(pl[j]);
            v = fmaxf(fmaf(v, sc[c0 + j], sh[c0 + j]), 0.f);
            split2(v, oh[j], ol[j]);
        }
        *(uint4*)(hi + o) = *(const uint4*)oh;
        *(uint4*)(lo + o) = *(const uint4*)ol;
    }
}

// ---------------- apply BN2 (+optional ReLU): h = Z*scale[c]+shift[c] ----------------
__global__ void bn_apply(const float* __restrict__ Z, float* __restrict__ H,
                         const float* __restrict__ scale, const float* __restrict__ shift,
                         int n4, int relu)
{
    int i = blockIdx.x * blockDim.x + threadIdx.x;
    int stride = gridDim.x * blockDim.x;
    for (; i < n4; i += stride) {
        float4 v = ((const float4*)Z)[i];
        int c0 = (i * 4) % DD;
        float4 o;
        o.x = fmaf(v.x, scale[c0 + 0], shift[c0 + 0]);
        o.y = fmaf(v.y, scale[c0 + 1], shift[c0 + 1]);
        o.z = fmaf(v.z, scale[c0 + 2], shift[c0 + 2]);
        o.w = fmaf(v.w, scale[c0 + 3], shift[c0 + 3]);
        if (relu) {
            o.x = fmaxf(o.x, 0.f); o.y = fmaxf(o.y, 0.f);
            o.z = fmaxf(o.z, 0.f); o.w = fmaxf(o.w, 0.f);
        }
        ((float4*)H)[i] = o;
    }
}

// ---------------- global_add_pool ----------------
__global__ __launch_bounds__(320) void pool_kernel(const float* __restrict__ h,
    const int* __restrict__ batch, int N, float* __restrict__ hg)
{
    int g = blockIdx.x;
    int lo = 0, hi = N;
    while (lo < hi) { int mid = (lo + hi) >> 1; if (batch[mid] < g) lo = mid + 1; else hi = mid; }
    int start = lo;
    hi = N;
    while (lo < hi) { int mid = (lo + hi) >> 1; if (batch[mid] <= g) lo = mid + 1; else hi = mid; }
    int end = lo;
    int d = threadIdx.x;
    if (d >= DD) return;
    float s = 0.f;
    for (int i = start; i < end; ++i) s += h[(size_t)i * DD + d];
    hg[(size_t)g * DD + d] = s;
}

// ---------------- GroupNorm + head ----------------
__global__ __launch_bounds__(256) void head_kernel(const float* __restrict__ hg,
    const float* __restrict__ w, const float* __restrict__ b, float* __restrict__ out)
{
    __shared__ float red[256];
    int g = blockIdx.x, t = threadIdx.x;
    const float* row = hg + (size_t)g * DD;
    float v0 = (t < DD) ? row[t] : 0.f;
    float v1 = (t + 256 < DD) ? row[t + 256] : 0.f;

    red[t] = v0 + v1;
    __syncthreads();
    for (int o = 128; o > 0; o >>= 1) { if (t < o) red[t] += red[t + o]; __syncthreads(); }
    float mean = red[0] * (1.f / (float)DD);
    __syncthreads();

    red[t] = v0 * v0 + v1 * v1;
    __syncthreads();
    for (int o = 128; o > 0; o >>= 1) { if (t < o) red[t] += red[t + o]; __syncthreads(); }
    float var = red[0] * (1.f / (float)DD) - mean * mean;
    float rs = rsqrtf(var + 1e-5f);
    __syncthreads();

    float d0 = (t < DD) ? (v0 - mean) * rs * w[t] : 0.f;
    float d1 = (t + 256 < DD) ? (v1 - mean) * rs * w[t + 256] : 0.f;
    red[t] = d0 + d1;
    __syncthreads();
    for (int o = 128; o > 0; o >>= 1) { if (t < o) red[t] += red[t + o]; __syncthreads(); }
    if (t == 0) out[g] = red[0] + b[0];
}

extern "C" void kernel_launch(void* const* d_in, const int* in_sizes, int n_in,
                              void* d_out, int out_size, void* d_ws, size_t ws_size,
                              hipStream_t stream)
{
    (void)n_in; (void)out_size; (void)ws_size;
    const int*   x         = (const int*)  d_in[0];
    const int*   edge_idx  = (const int*)  d_in[1];
    const int*   edge_attr = (const int*)  d_in[2];
    const int*   batch     = (const int*)  d_in[3];
    const float* atom_emb  = (const float*)d_in[4];
    const float* bond_emb  = (const float*)d_in[5];
    const float* eps       = (const float*)d_in[6];
    const float* W1        = (const float*)d_in[7];
    const float* b1        = (const float*)d_in[8];
    const float* g1        = (const float*)d_in[9];
    const float* be1       = (const float*)d_in[10];
    const float* W2        = (const float*)d_in[11];
    const float* b2        = (const float*)d_in[12];
    const float* g2        = (const float*)d_in[13];
    const float* be2       = (const float*)d_in[14];
    const float* head_w    = (const float*)d_in[15];
    const float* head_b    = (const float*)d_in[16];

    const int NN = in_sizes[3];          // nodes (20000)
    const int E  = in_sizes[1] / 2;      // edges (320000)
    const int gm = (NN + 127) / 128;     // 157 M-blocks
    const int mpad = gm * 128;           // 20096

    char* p = (char*)d_ws;
    auto alloc = [&](size_t bytes) { char* r = p; p += (bytes + 255) & ~(size_t)255; return r; };

    float* h    = (float*)alloc((size_t)NN * DD * 4);
    u16* A1hi   = (u16*)  alloc((size_t)mpad * KP1 * 2);
    u16* A1lo   = (u16*)  alloc((size_t)mpad * KP1 * 2);
    float* zb2  = (float*)A1hi;   // alias: zb2 (N*300 f32) reuses A1hi+A1lo; safe by stream order
    u16* Z1hi   = (u16*)  alloc((size_t)mpad * KP2 * 2);
    u16* Z1lo   = (u16*)  alloc((size_t)mpad * KP2 * 2);
    u16* W1Thi  = (u16*)  alloc((size_t)LL * NP1 * KP1 * 2);
    u16* W1Tlo  = (u16*)  alloc((size_t)LL * NP1 * KP1 * 2);
    u16* W2Thi  = (u16*)  alloc((size_t)LL * NP2 * KP2 * 2);
    u16* W2Tlo  = (u16*)  alloc((size_t)LL * NP2 * KP2 * 2);
    float* combo= (float*)alloc((size_t)LL * 512 * DD * 4);
    float* hg   = (float*)alloc((size_t)NGG * DD * 4);
    float* cs   = (float*)alloc(HH * 4 * 2);     // cs+csq contiguous
    float* csq  = cs + HH;
    float* sc1  = (float*)alloc(HH * 4);
    float* sh1  = (float*)alloc(HH * 4);
    float* sc2  = (float*)alloc(DD * 4);
    float* sh2  = (float*)alloc(DD * 4);
    int* cnt    = (int*)  alloc((size_t)NN * 4 * 2);   // cnt+cursor contiguous
    int* cursor = cnt + NN;
    int* rowptr = (int*)  alloc((size_t)(NN + 1) * 4);
    int* rec    = (int*)  alloc((size_t)E * 4);

    const int* src = edge_idx;
    const int* dst = edge_idx + E;

    // ---- per-call setup ----
    hipMemsetAsync(cnt, 0, (size_t)NN * 2 * sizeof(int), stream);
    hipMemsetAsync(cs, 0, (size_t)HH * 2 * sizeof(float), stream);
    csr_count<<<512, 256, 0, stream>>>(dst, E, cnt);
    scan_kernel<<<1, 1024, 0, stream>>>(cnt, rowptr, NN);
    csr_fill<<<512, 256, 0, stream>>>(src, dst, edge_attr, rowptr, cursor, rec, E);
    combo_build<<<LL * 512, 320, 0, stream>>>(bond_emb, combo);
    w_prep_t<<<LL * (KP1 / 64) * (NP1 / 64), 256, 0, stream>>>(
        W1, DD, HH, KP1, NP1, KP1 / 64, W1Thi, W1Tlo);
    w_prep_t<<<LL * ((KP2 + 63) / 64) * (NP2 / 64), 256, 0, stream>>>(
        W2, HH, DD, KP2, NP2, (KP2 + 63) / 64, W2Thi, W2Tlo);
    atom_kernel<<<NN, 320, 0, stream>>>(x, atom_emb, h, NN);

    for (int l = 0; l < LL; ++l) {
        agg_kernel<<<NN, 320, 0, stream>>>(h, rec, rowptr,
            combo + (size_t)l * 512 * DD, eps, l, A1hi, A1lo);

        gemm_mfma<1><<<dim3(gm, NP1 / 128), 256, 0, stream>>>(
            A1hi, A1lo, KP1,
            W1Thi + (size_t)l * NP1 * KP1, W1Tlo + (size_t)l * NP1 * KP1,
            b1 + (size_t)l * HH, NN, HH, KP1 / 32,
            nullptr, Z1hi, Z1lo, KP2);

        colstats_bf<<<(NN + 63) / 64, 256, 0, stream>>>(Z1hi, Z1lo, NN, HH, KP2, cs, csq, 64);
        bn_fin<<<(HH + 255) / 256, 256, 0, stream>>>(cs, csq, g1 + (size_t)l * HH,
            be1 + (size_t)l * HH, sc1, sh1, HH, 1.f / (float)NN);

        bn1_split<<<2048, 256, 0, stream>>>(Z1hi, Z1lo, sc1, sh1, NN);

        gemm_mfma<0><<<dim3(gm, NP2 / 128), 256, 0, stream>>>(
            Z1hi, Z1lo, KP2,
            W2Thi + (size_t)l * NP2 * KP2, W2Tlo + (size_t)l * NP2 * KP2,
            b2 + (size_t)l * DD, NN, DD, KP2 / 32,
            zb2, nullptr, nullptr, 0);

        colstats<<<(NN + 63) / 64, 256, 0, stream>>>(zb2, NN, DD, cs, csq, 64);
        bn_fin<<<(DD + 255) / 256, 256, 0, stream>>>(cs, csq, g2 + (size_t)l * DD,
            be2 + (size_t)l * DD, sc2, sh2, DD, 1.f / (float)NN);

        bn_apply<<<1024, 256, 0, stream>>>(zb2, h, sc2, sh2, NN * DD / 4, (l < LL - 1) ? 1 : 0);
    }

    pool_kernel<<<NGG, 320, 0, stream>>>(h, batch, NN, hg);
    head_kernel<<<NGG, 256, 0, stream>>>(hg, head_w, head_b, (float*)d_out);
}

// Round 5
// 1584.811 us; speedup vs baseline: 2.4598x; 1.1269x over previous
//
#include <hip/hip_runtime.h>
#include <cstddef>
#include <cstdint>

#define DD 300
#define HH 600
#define LL 5
#define NGG 512
#define KP1 320     // padded K for GEMM1 (D=300 -> 10 K-steps of 32)
#define KP2 608     // padded K for GEMM2 (H=600 -> 19 K-steps of 32)
#define NP1 640     // padded N of W1^T (600 -> 5 col-blocks of 128)
#define NP2 384     // padded N of W2^T (300 -> 3 col-blocks of 128)

typedef unsigned short u16;
typedef short bf16x8 __attribute__((ext_vector_type(8)));
typedef float f32x4 __attribute__((ext_vector_type(4)));

__device__ __forceinline__ float bf2f(u16 h) { return __uint_as_float(((unsigned)h) << 16); }

// RNE split: v = hi + lo (two bf16, ~16 mantissa bits total)
__device__ __forceinline__ void split2(float v, u16& hi, u16& lo)
{
    unsigned u = __float_as_uint(v);
    unsigned r = (u + 0x7FFFu + ((u >> 16) & 1u)) >> 16;
    hi = (u16)r;
    float res = v - __uint_as_float(r << 16);
    unsigned u2 = __float_as_uint(res);
    lo = (u16)((u2 + 0x7FFFu + ((u2 >> 16) & 1u)) >> 16);
}

__device__ __forceinline__ void g2l16(const void* g, void* l)
{
    __builtin_amdgcn_global_load_lds(
        (const __attribute__((address_space(1))) void*)g,
        (__attribute__((address_space(3))) void*)l, 16, 0, 0);
}

// ---------------- Atom encoder ----------------
__global__ __launch_bounds__(320) void atom_kernel(const int* __restrict__ x,
    const float* __restrict__ emb, float* __restrict__ h, int N)
{
    __shared__ int xi[9];
    int n = blockIdx.x;
    int t = threadIdx.x;
    if (t < 9) xi[t] = x[n * 9 + t] + t * 64;
    __syncthreads();
    if (t >= DD) return;
    float s = 0.f;
#pragma unroll
    for (int f = 0; f < 9; ++f) s += emb[(size_t)xi[f] * DD + t];
    h[(size_t)n * DD + t] = s;
}

// ---------------- CSR build ----------------
__global__ void csr_count(const int* __restrict__ dst, int E, int* __restrict__ cnt)
{
    int i = blockIdx.x * blockDim.x + threadIdx.x;
    int stride = gridDim.x * blockDim.x;
    for (; i < E; i += stride) atomicAdd(&cnt[dst[i]], 1);
}

__global__ __launch_bounds__(1024) void scan_kernel(const int* __restrict__ cnt,
    int* __restrict__ rowptr, int n)
{
    __shared__ int buf[1024];
    int t = threadIdx.x;
    int carry = 0;
    for (int base = 0; base < n; base += 1024) {
        int v = (base + t < n) ? cnt[base + t] : 0;
        buf[t] = v;
        __syncthreads();
        for (int off = 1; off < 1024; off <<= 1) {
            int x = (t >= off) ? buf[t - off] : 0;
            __syncthreads();
            buf[t] += x;
            __syncthreads();
        }
        if (base + t < n) rowptr[base + t] = buf[t] - v + carry;
        int total = buf[1023];
        __syncthreads();
        carry += total;
    }
    if (t == 0) rowptr[n] = carry;
}

__global__ void csr_fill(const int* __restrict__ src, const int* __restrict__ dst,
    const int* __restrict__ ea, const int* __restrict__ rowptr,
    int* __restrict__ cursor, int* __restrict__ rec, int E)
{
    int i = blockIdx.x * blockDim.x + threadIdx.x;
    int stride = gridDim.x * blockDim.x;
    for (; i < E; i += stride) {
        int d = dst[i];
        int pos = rowptr[d] + atomicAdd(&cursor[d], 1);
        int code = ea[i * 3] | (ea[i * 3 + 1] << 3) | (ea[i * 3 + 2] << 6);
        rec[pos] = src[i] | (code << 20);
    }
}

// ---------------- per-layer bond-code combo table ----------------
__global__ __launch_bounds__(320) void combo_build(const float* __restrict__ bond,
    float* __restrict__ combo)
{
    int blk = blockIdx.x;           // l*512 + code
    int l = blk >> 9, code = blk & 511;
    int t = threadIdx.x;
    if (t >= DD) return;
    const float* bl = bond + (size_t)l * 24 * DD;
    combo[(size_t)blk * DD + t] = bl[(size_t)(code & 7) * DD + t]
                                + bl[(size_t)(8 + ((code >> 3) & 7)) * DD + t]
                                + bl[(size_t)(16 + (code >> 6)) * DD + t];
}

// ---------------- LDS-tiled weight transpose + bf16-split, zero-padded ----------------
// W [L][K][N] fp32 -> T [L][NPp][KPp] bf16 hi/lo with T[l][n][k] = W[l][k][n]
__global__ __launch_bounds__(256) void w_prep_t(const float* __restrict__ W,
    int K, int N, int KPp, int NPp, int ktiles,
    u16* __restrict__ Thi, u16* __restrict__ Tlo)
{
    __shared__ float tile[64][65];
    int ntiles = NPp >> 6;
    int blk = blockIdx.x;            // l*ktiles*ntiles + kt*ntiles + nt
    int l = blk / (ktiles * ntiles);
    int rem = blk % (ktiles * ntiles);
    int k0 = (rem / ntiles) << 6;
    int n0 = (rem % ntiles) << 6;
    int tn = threadIdx.x & 63;
    int tg = threadIdx.x >> 6;       // 0..3
    const float* Wl = W + (size_t)l * K * N;
    for (int kk = tg; kk < 64; kk += 4) {
        int gk = k0 + kk, gn = n0 + tn;
        tile[kk][tn] = (gk < K && gn < N) ? Wl[(size_t)gk * N + gn] : 0.f;
    }
    __syncthreads();
    for (int nn = tg; nn < 64; nn += 4) {
        int gn = n0 + nn, gk = k0 + tn;
        if (gk < KPp) {
            u16 hi, lo; split2(tile[tn][nn], hi, lo);
            size_t o = ((size_t)l * NPp + gn) * KPp + gk;
            Thi[o] = hi; Tlo[o] = lo;
        }
    }
}

// ---------------- fused aggregate + GIN update -> fp32 A1 (unroll-4 MLP) ----------------
__global__ __launch_bounds__(320) void agg_kernel(const float* __restrict__ h,
    const int* __restrict__ rec, const int* __restrict__ rowptr,
    const float* __restrict__ combo_l, const float* __restrict__ eps, int l,
    float* __restrict__ zf)
{
    int n = blockIdx.x;
    int t = threadIdx.x;
    if (t >= DD) {
        if (t < KP1) zf[(size_t)n * KP1 + t] = 0.f;
        return;
    }
    int beg = rowptr[n], end = rowptr[n + 1];
    float acc = 0.f;
    int i = beg;
    for (; i + 4 <= end; i += 4) {
        int r0 = rec[i], r1 = rec[i + 1], r2 = rec[i + 2], r3 = rec[i + 3];
        const float* p0 = h + (size_t)(r0 & 0xFFFFF) * DD;
        const float* p1 = h + (size_t)(r1 & 0xFFFFF) * DD;
        const float* p2 = h + (size_t)(r2 & 0xFFFFF) * DD;
        const float* p3 = h + (size_t)(r3 & 0xFFFFF) * DD;
        const float* q0 = combo_l + (size_t)(((unsigned)r0) >> 20) * DD;
        const float* q1 = combo_l + (size_t)(((unsigned)r1) >> 20) * DD;
        const float* q2 = combo_l + (size_t)(((unsigned)r2) >> 20) * DD;
        const float* q3 = combo_l + (size_t)(((unsigned)r3) >> 20) * DD;
        float h0 = p0[t], h1 = p1[t], h2 = p2[t], h3 = p3[t];
        float c0 = q0[t], c1 = q1[t], c2 = q2[t], c3 = q3[t];
        acc += fmaxf(h0 + c0, 0.f) + fmaxf(h1 + c1, 0.f)
             + fmaxf(h2 + c2, 0.f) + fmaxf(h3 + c3, 0.f);
    }
    for (; i < end; ++i) {
        int r = rec[i];
        float v = h[(size_t)(r & 0xFFFFF) * DD + t]
                + combo_l[(size_t)(((unsigned)r) >> 20) * DD + t];
        acc += fmaxf(v, 0.f);
    }
    float se = 1.0f + eps[l];
    zf[(size_t)n * KP1 + t] = fmaf(se, h[(size_t)n * DD + t], acc);
}

// ---------------- split-bf16 MFMA GEMM, reg-staged fp32 A, dbuf LDS ----------------
// C[M,N] = op(A)[M,K] @ B[N,K]^T + bias, op = FUSE ? relu(A*sc[k]+sh[k]) : A
// A fp32 [.][lda]; B split-bf16 [NPp][lda]. 128x128 tile, 8 waves (2x4 of 64x32).
// Out fp32 [.][ldc]; cols N..ldc zero-padded.
template <bool FUSE>
__global__ __launch_bounds__(512, 4) void gemm_rs(
    const float* __restrict__ Af, int lda,
    const u16* __restrict__ Bhi, const u16* __restrict__ Blo,
    const float* __restrict__ bias,
    const float* __restrict__ scA, const float* __restrict__ shA,
    float* __restrict__ C, int ldc, int M, int N, int ksteps)
{
    __shared__ __align__(16) u16 Ah[2][4][128][8];
    __shared__ __align__(16) u16 Al[2][4][128][8];
    __shared__ __align__(16) u16 Bh[2][4][128][8];
    __shared__ __align__(16) u16 Bl[2][4][128][8];
    __shared__ float sc_s[640], sh_s[640];

    const int t = threadIdx.x;
    const int lane = t & 63, w = t >> 6;
    const int l15 = lane & 15, l4 = lane >> 4;
    const int wr = w >> 2, wc = w & 3;          // wave tile: 64 rows x 32 cols
    const int col0 = blockIdx.x * 128;
    const int row0 = blockIdx.y * 128;

    if (FUSE) {
        for (int c = t; c < lda; c += 512) { sc_s[c] = scA[c]; sh_s[c] = shA[c]; }
    }

    const int arow = t >> 2;            // 0..127
    const int kg   = t & 3;             // 0..3
    const int k8   = kg * 8;
    const float* aptr = Af + (size_t)(row0 + arow) * lda + k8;

    const int bkg = w >> 1, bch = w & 1;
    const u16* bhptr = Bhi + (size_t)(col0 + bch * 64 + lane) * lda + bkg * 8;
    const u16* blptr = Blo + (size_t)(col0 + bch * 64 + lane) * lda + bkg * 8;

    float4 pv0, pv1;
    auto loadA = [&](int ks) {
        const float* p = aptr + ks * 32;
        pv0 = *(const float4*)p;
        pv1 = *(const float4*)(p + 4);
    };
    auto issueB = [&](int ks, int buf) {
        g2l16(bhptr + ks * 32, &Bh[buf][bkg][bch * 64][0]);
        g2l16(blptr + ks * 32, &Bl[buf][bkg][bch * 64][0]);
    };
    auto writeA = [&](int ks, int buf) {
        float v[8] = {pv0.x, pv0.y, pv0.z, pv0.w, pv1.x, pv1.y, pv1.z, pv1.w};
        u16 oh[8], ol[8];
#pragma unroll
        for (int j = 0; j < 8; ++j) {
            float xv = v[j];
            if (FUSE) {
                int c = ks * 32 + k8 + j;
                xv = fmaxf(fmaf(xv, sc_s[c], sh_s[c]), 0.f);
            }
            split2(xv, oh[j], ol[j]);
        }
        *(uint4*)&Ah[buf][kg][arow][0] = *(const uint4*)oh;
        *(uint4*)&Al[buf][kg][arow][0] = *(const uint4*)ol;
    };

    f32x4 acc[4][2];
#pragma unroll
    for (int i = 0; i < 4; ++i)
#pragma unroll
        for (int j = 0; j < 2; ++j) acc[i][j] = (f32x4){0.f, 0.f, 0.f, 0.f};

    __syncthreads();                    // sc_s visible
    loadA(0); issueB(0, 0); writeA(0, 0);
    __syncthreads();                    // drain g2l16 + ds_writes

    int cur = 0;
    for (int ks = 0; ks < ksteps; ++ks) {
        int nxt = cur ^ 1;
        bool more = (ks + 1 < ksteps);
        if (more) { loadA(ks + 1); issueB(ks + 1, nxt); }

        bf16x8 a_h[4], a_l[4], b_h[2], b_l[2];
#pragma unroll
        for (int i = 0; i < 4; ++i) {
            int r = wr * 64 + i * 16 + l15;
            a_h[i] = *(const bf16x8*)Ah[cur][l4][r];
            a_l[i] = *(const bf16x8*)Al[cur][l4][r];
        }
#pragma unroll
        for (int i = 0; i < 2; ++i) {
            int c = wc * 32 + i * 16 + l15;
            b_h[i] = *(const bf16x8*)Bh[cur][l4][c];
            b_l[i] = *(const bf16x8*)Bl[cur][l4][c];
        }
#pragma unroll
        for (int mi = 0; mi < 4; ++mi)
#pragma unroll
            for (int ni = 0; ni < 2; ++ni) {
                acc[mi][ni] = __builtin_amdgcn_mfma_f32_16x16x32_bf16(a_h[mi], b_h[ni], acc[mi][ni], 0, 0, 0);
                acc[mi][ni] = __builtin_amdgcn_mfma_f32_16x16x32_bf16(a_h[mi], b_l[ni], acc[mi][ni], 0, 0, 0);
                acc[mi][ni] = __builtin_amdgcn_mfma_f32_16x16x32_bf16(a_l[mi], b_h[ni], acc[mi][ni], 0, 0, 0);
            }

        if (more) writeA(ks + 1, nxt);
        __syncthreads();
        cur = nxt;
    }

#pragma unroll
    for (int mi = 0; mi < 4; ++mi)
#pragma unroll
        for (int ni = 0; ni < 2; ++ni)
#pragma unroll
            for (int r = 0; r < 4; ++r) {
                int gr = row0 + wr * 64 + mi * 16 + l4 * 4 + r;
                int gc = col0 + wc * 32 + ni * 16 + l15;
                if (gr >= M) continue;
                if (gc < N)        C[(size_t)gr * ldc + gc] = acc[mi][ni][r] + bias[gc];
                else if (gc < ldc) C[(size_t)gr * ldc + gc] = 0.f;
            }
}

// ---------------- column stats fp32 (strided) ----------------
__global__ __launch_bounds__(256) void colstats(const float* __restrict__ Mx,
    int rows, int cols, int stride,
    float* __restrict__ cs, float* __restrict__ csq, int rpb)
{
    int r0 = blockIdx.x * rpb;
    int r1 = min(r0 + rpb, rows);
    int t = threadIdx.x;
    float s[3] = {0.f, 0.f, 0.f}, q[3] = {0.f, 0.f, 0.f};
    for (int r = r0; r < r1; ++r) {
        const float* row = Mx + (size_t)r * stride;
#pragma unroll
        for (int ci = 0; ci < 3; ++ci) {
            int c = t + ci * 256;
            if (c < cols) { float v = row[c]; s[ci] += v; q[ci] += v * v; }
        }
    }
#pragma unroll
    for (int ci = 0; ci < 3; ++ci) {
        int c = t + ci * 256;
        if (c < cols) { atomicAdd(&cs[c], s[ci]); atomicAdd(&csq[c], q[ci]); }
    }
}

// ---------------- finalize BN; zero pad cols; self-clean stats buffers ----------------
__global__ void bn_fin(float* __restrict__ cs, float* __restrict__ csq,
                       const float* __restrict__ g, const float* __restrict__ be,
                       float* __restrict__ scale, float* __restrict__ shift,
                       int cols, int colspad, float invn)
{
    int c = blockIdx.x * blockDim.x + threadIdx.x;
    if (c >= colspad) return;
    if (c >= cols) { scale[c] = 0.f; shift[c] = 0.f; return; }
    float mu = cs[c] * invn;
    float var = csq[c] * invn - mu * mu;
    float rs = rsqrtf(var + 1e-5f);
    float sc = rs * g[c];
    scale[c] = sc;
    shift[c] = be[c] - mu * sc;
    cs[c] = 0.f;
    csq[c] = 0.f;
}

// ---------------- apply BN2 (+optional ReLU): h = Z*scale[c]+shift[c] ----------------
__global__ void bn_apply(const float* __restrict__ Z, float* __restrict__ H,
                         const float* __restrict__ scale, const float* __restrict__ shift,
                         int n4, int relu)
{
    int i = blockIdx.x * blockDim.x + threadIdx.x;
    int stride = gridDim.x * blockDim.x;
    for (; i < n4; i += stride) {
        float4 v = ((const float4*)Z)[i];
        int c0 = (i * 4) % DD;
        float4 o;
        o.x = fmaf(v.x, scale[c0 + 0], shift[c0 + 0]);
        o.y = fmaf(v.y, scale[c0 + 1], shift[c0 + 1]);
        o.z = fmaf(v.z, scale[c0 + 2], shift[c0 + 2]);
        o.w = fmaf(v.w, scale[c0 + 3], shift[c0 + 3]);
        if (relu) {
            o.x = fmaxf(o.x, 0.f); o.y = fmaxf(o.y, 0.f);
            o.z = fmaxf(o.z, 0.f); o.w = fmaxf(o.w, 0.f);
        }
        ((float4*)H)[i] = o;
    }
}

// ---------------- global_add_pool ----------------
__global__ __launch_bounds__(320) void pool_kernel(const float* __restrict__ h,
    const int* __restrict__ batch, int N, float* __restrict__ hg)
{
    int g = blockIdx.x;
    int lo = 0, hi = N;
    while (lo < hi) { int mid = (lo + hi) >> 1; if (batch[mid] < g) lo = mid + 1; else hi = mid; }
    int start = lo;
    hi = N;
    while (lo < hi) { int mid = (lo + hi) >> 1; if (batch[mid] <= g) lo = mid + 1; else hi = mid; }
    int end = lo;
    int d = threadIdx.x;
    if (d >= DD) return;
    float s = 0.f;
    for (int i = start; i < end; ++i) s += h[(size_t)i * DD + d];
    hg[(size_t)g * DD + d] = s;
}

// ---------------- GroupNorm + head ----------------
__global__ __launch_bounds__(256) void head_kernel(const float* __restrict__ hg,
    const float* __restrict__ w, const float* __restrict__ b, float* __restrict__ out)
{
    __shared__ float red[256];
    int g = blockIdx.x, t = threadIdx.x;
    const float* row = hg + (size_t)g * DD;
    float v0 = (t < DD) ? row[t] : 0.f;
    float v1 = (t + 256 < DD) ? row[t + 256] : 0.f;

    red[t] = v0 + v1;
    __syncthreads();
    for (int o = 128; o > 0; o >>= 1) { if (t < o) red[t] += red[t + o]; __syncthreads(); }
    float mean = red[0] * (1.f / (float)DD);
    __syncthreads();

    red[t] = v0 * v0 + v1 * v1;
    __syncthreads();
    for (int o = 128; o > 0; o >>= 1) { if (t < o) red[t] += red[t + o]; __syncthreads(); }
    float var = red[0] * (1.f / (float)DD) - mean * mean;
    float rs = rsqrtf(var + 1e-5f);
    __syncthreads();

    float d0 = (t < DD) ? (v0 - mean) * rs * w[t] : 0.f;
    float d1 = (t + 256 < DD) ? (v1 - mean) * rs * w[t + 256] : 0.f;
    red[t] = d0 + d1;
    __syncthreads();
    for (int o = 128; o > 0; o >>= 1) { if (t < o) red[t] += red[t + o]; __syncthreads(); }
    if (t == 0) out[g] = red[0] + b[0];
}

extern "C" void kernel_launch(void* const* d_in, const int* in_sizes, int n_in,
                              void* d_out, int out_size, void* d_ws, size_t ws_size,
                              hipStream_t stream)
{
    (void)n_in; (void)out_size; (void)ws_size;
    const int*   x         = (const int*)  d_in[0];
    const int*   edge_idx  = (const int*)  d_in[1];
    const int*   edge_attr = (const int*)  d_in[2];
    const int*   batch     = (const int*)  d_in[3];
    const float* atom_emb  = (const float*)d_in[4];
    const float* bond_emb  = (const float*)d_in[5];
    const float* eps       = (const float*)d_in[6];
    const float* W1        = (const float*)d_in[7];
    const float* b1        = (const float*)d_in[8];
    const float* g1        = (const float*)d_in[9];
    const float* be1       = (const float*)d_in[10];
    const float* W2        = (const float*)d_in[11];
    const float* b2        = (const float*)d_in[12];
    const float* g2        = (const float*)d_in[13];
    const float* be2       = (const float*)d_in[14];
    const float* head_w    = (const float*)d_in[15];
    const float* head_b    = (const float*)d_in[16];

    const int NN = in_sizes[3];          // nodes (20000)
    const int E  = in_sizes[1] / 2;      // edges (320000)
    const int gm = (NN + 127) / 128;     // 157 row-blocks
    const int mpad = gm * 128;           // 20096

    char* p = (char*)d_ws;
    auto alloc = [&](size_t bytes) { char* r = p; p += (bytes + 255) & ~(size_t)255; return r; };

    float* h    = (float*)alloc((size_t)NN * DD * 4);
    float* A1f  = (float*)alloc((size_t)mpad * KP1 * 4);    // fp32 GIN-z, lda=KP1
    float* zb2  = A1f;            // alias: zb2 (NN*300 f32) reuses A1f; safe by stream order
    float* Z1   = (float*)alloc((size_t)mpad * KP2 * 4);    // fp32 Z1, lda=KP2
    u16* W1Thi  = (u16*)  alloc((size_t)LL * NP1 * KP1 * 2);
    u16* W1Tlo  = (u16*)  alloc((size_t)LL * NP1 * KP1 * 2);
    u16* W2Thi  = (u16*)  alloc((size_t)LL * NP2 * KP2 * 2);
    u16* W2Tlo  = (u16*)  alloc((size_t)LL * NP2 * KP2 * 2);
    float* combo= (float*)alloc((size_t)LL * 512 * DD * 4);
    float* hg   = (float*)alloc((size_t)NGG * DD * 4);
    float* cs   = (float*)alloc(HH * 4 * 2);     // cs+csq contiguous
    float* csq  = cs + HH;
    float* sc1  = (float*)alloc(640 * 4);
    float* sh1  = (float*)alloc(640 * 4);
    float* sc2  = (float*)alloc(DD * 4);
    float* sh2  = (float*)alloc(DD * 4);
    int* cnt    = (int*)  alloc((size_t)NN * 4 * 2);   // cnt+cursor contiguous
    int* cursor = cnt + NN;
    int* rowptr = (int*)  alloc((size_t)(NN + 1) * 4);
    int* rec    = (int*)  alloc((size_t)E * 4);

    const int* src = edge_idx;
    const int* dst = edge_idx + E;

    // ---- per-call setup ----
    hipMemsetAsync(cnt, 0, (size_t)NN * 2 * sizeof(int), stream);
    hipMemsetAsync(cs, 0, (size_t)HH * 2 * sizeof(float), stream);
    csr_count<<<512, 256, 0, stream>>>(dst, E, cnt);
    scan_kernel<<<1, 1024, 0, stream>>>(cnt, rowptr, NN);
    csr_fill<<<512, 256, 0, stream>>>(src, dst, edge_attr, rowptr, cursor, rec, E);
    combo_build<<<LL * 512, 320, 0, stream>>>(bond_emb, combo);
    w_prep_t<<<LL * (KP1 / 64) * (NP1 / 64), 256, 0, stream>>>(
        W1, DD, HH, KP1, NP1, KP1 / 64, W1Thi, W1Tlo);
    w_prep_t<<<LL * ((KP2 + 63) / 64) * (NP2 / 64), 256, 0, stream>>>(
        W2, HH, DD, KP2, NP2, (KP2 + 63) / 64, W2Thi, W2Tlo);
    atom_kernel<<<NN, 320, 0, stream>>>(x, atom_emb, h, NN);

    for (int l = 0; l < LL; ++l) {
        agg_kernel<<<NN, 320, 0, stream>>>(h, rec, rowptr,
            combo + (size_t)l * 512 * DD, eps, l, A1f);

        gemm_rs<false><<<dim3(NP1 / 128, gm), 512, 0, stream>>>(
            A1f, KP1,
            W1Thi + (size_t)l * NP1 * KP1, W1Tlo + (size_t)l * NP1 * KP1,
            b1 + (size_t)l * HH, nullptr, nullptr,
            Z1, KP2, NN, HH, KP1 / 32);

        colstats<<<(NN + 63) / 64, 256, 0, stream>>>(Z1, NN, HH, KP2, cs, csq, 64);
        bn_fin<<<(KP2 + 255) / 256, 256, 0, stream>>>(cs, csq, g1 + (size_t)l * HH,
            be1 + (size_t)l * HH, sc1, sh1, HH, KP2, 1.f / (float)NN);

        gemm_rs<true><<<dim3(NP2 / 128, gm), 512, 0, stream>>>(
            Z1, KP2,
            W2Thi + (size_t)l * NP2 * KP2, W2Tlo + (size_t)l * NP2 * KP2,
            b2 + (size_t)l * DD, sc1, sh1,
            zb2, DD, NN, DD, KP2 / 32);

        colstats<<<(NN + 63) / 64, 256, 0, stream>>>(zb2, NN, DD, DD, cs, csq, 64);
        bn_fin<<<(DD + 255) / 256, 256, 0, stream>>>(cs, csq, g2 + (size_t)l * DD,
            be2 + (size_t)l * DD, sc2, sh2, DD, DD, 1.f / (float)NN);

        bn_apply<<<1024, 256, 0, stream>>>(zb2, h, sc2, sh2, NN * DD / 4, (l < LL - 1) ? 1 : 0);
    }

    pool_kernel<<<NGG, 320, 0, stream>>>(h, batch, NN, hg);
    head_kernel<<<NGG, 256, 0, stream>>>(hg, head_w, head_b, (float*)d_out);
}

// Round 6
// 985.078 us; speedup vs baseline: 3.9573x; 1.6088x over previous
//
#include <hip/hip_runtime.h>
#include <cstddef>
#include <cstdint>

#define DD 300
#define HH 600
#define LL 5
#define NGG 512
#define KP1 320     // padded K for GEMM1 (fp16 A row stride)
#define KP2 608     // padded K for GEMM2 (fp16 Z1 row stride)
#define NP1 640     // padded N of W1^T (600 -> 5 col-blocks of 128)
#define NP2 384     // padded N of W2^T (300 -> 3 col-blocks of 128)
#define Z2LD 304    // fp16 z2/h row stride

typedef unsigned short u16;
typedef short bf16x8 __attribute__((ext_vector_type(8)));
typedef float f32x4 __attribute__((ext_vector_type(4)));

// RNE split: v = hi + lo (two bf16, ~16 mantissa bits total)
__device__ __forceinline__ void split2(float v, u16& hi, u16& lo)
{
    unsigned u = __float_as_uint(v);
    unsigned r = (u + 0x7FFFu + ((u >> 16) & 1u)) >> 16;
    hi = (u16)r;
    float res = v - __uint_as_float(r << 16);
    unsigned u2 = __float_as_uint(res);
    lo = (u16)((u2 + 0x7FFFu + ((u2 >> 16) & 1u)) >> 16);
}

__device__ __forceinline__ u16 f2h(float v)
{
    _Float16 h = (_Float16)v; u16 u; __builtin_memcpy(&u, &h, 2); return u;
}
__device__ __forceinline__ float h2f(u16 u)
{
    _Float16 h; __builtin_memcpy(&h, &u, 2); return (float)h;
}

__device__ __forceinline__ void g2l16(const void* g, void* l)
{
    __builtin_amdgcn_global_load_lds(
        (const __attribute__((address_space(1))) void*)g,
        (__attribute__((address_space(3))) void*)l, 16, 0, 0);
}

// ---------------- Atom encoder -> fp16 z2 (layer-0 gather source) ----------------
__global__ __launch_bounds__(320) void atom_kernel(const int* __restrict__ x,
    const float* __restrict__ emb, u16* __restrict__ z2, int N)
{
    __shared__ int xi[9];
    int n = blockIdx.x;
    int t = threadIdx.x;
    if (t < 9) xi[t] = x[n * 9 + t] + t * 64;
    __syncthreads();
    if (t >= DD) return;
    float s = 0.f;
#pragma unroll
    for (int f = 0; f < 9; ++f) s += emb[(size_t)xi[f] * DD + t];
    z2[(size_t)n * Z2LD + t] = f2h(s);
}

// ---------------- CSR build ----------------
__global__ void csr_count(const int* __restrict__ dst, int E, int* __restrict__ cnt)
{
    int i = blockIdx.x * blockDim.x + threadIdx.x;
    int stride = gridDim.x * blockDim.x;
    for (; i < E; i += stride) atomicAdd(&cnt[dst[i]], 1);
}

__global__ __launch_bounds__(1024) void scan_kernel(const int* __restrict__ cnt,
    int* __restrict__ rowptr, int n)
{
    __shared__ int buf[1024];
    int t = threadIdx.x;
    int carry = 0;
    for (int base = 0; base < n; base += 1024) {
        int v = (base + t < n) ? cnt[base + t] : 0;
        buf[t] = v;
        __syncthreads();
        for (int off = 1; off < 1024; off <<= 1) {
            int x = (t >= off) ? buf[t - off] : 0;
            __syncthreads();
            buf[t] += x;
            __syncthreads();
        }
        if (base + t < n) rowptr[base + t] = buf[t] - v + carry;
        int total = buf[1023];
        __syncthreads();
        carry += total;
    }
    if (t == 0) rowptr[n] = carry;
}

__global__ void csr_fill(const int* __restrict__ src, const int* __restrict__ dst,
    const int* __restrict__ ea, const int* __restrict__ rowptr,
    int* __restrict__ cursor, int* __restrict__ rec, int E)
{
    int i = blockIdx.x * blockDim.x + threadIdx.x;
    int stride = gridDim.x * blockDim.x;
    for (; i < E; i += stride) {
        int d = dst[i];
        int pos = rowptr[d] + atomicAdd(&cursor[d], 1);
        int code = ea[i * 3] | (ea[i * 3 + 1] << 3) | (ea[i * 3 + 2] << 6);
        rec[pos] = src[i] | (code << 20);
    }
}

// ---------------- per-layer bond-code combo table (fp16) ----------------
__global__ __launch_bounds__(320) void combo_build(const float* __restrict__ bond,
    u16* __restrict__ combo)
{
    int blk = blockIdx.x;           // l*512 + code
    int l = blk >> 9, code = blk & 511;
    int t = threadIdx.x;
    if (t >= DD) return;
    const float* bl = bond + (size_t)l * 24 * DD;
    float v = bl[(size_t)(code & 7) * DD + t]
            + bl[(size_t)(8 + ((code >> 3) & 7)) * DD + t]
            + bl[(size_t)(16 + (code >> 6)) * DD + t];
    combo[(size_t)blk * DD + t] = f2h(v);
}

// ---------------- LDS-tiled weight transpose + bf16-split, zero-padded ----------------
__global__ __launch_bounds__(256) void w_prep_t(const float* __restrict__ W,
    int K, int N, int KPp, int NPp, int ktiles,
    u16* __restrict__ Thi, u16* __restrict__ Tlo)
{
    __shared__ float tile[64][65];
    int ntiles = NPp >> 6;
    int blk = blockIdx.x;
    int l = blk / (ktiles * ntiles);
    int rem = blk % (ktiles * ntiles);
    int k0 = (rem / ntiles) << 6;
    int n0 = (rem % ntiles) << 6;
    int tn = threadIdx.x & 63;
    int tg = threadIdx.x >> 6;
    const float* Wl = W + (size_t)l * K * N;
    for (int kk = tg; kk < 64; kk += 4) {
        int gk = k0 + kk, gn = n0 + tn;
        tile[kk][tn] = (gk < K && gn < N) ? Wl[(size_t)gk * N + gn] : 0.f;
    }
    __syncthreads();
    for (int nn = tg; nn < 64; nn += 4) {
        int gn = n0 + nn, gk = k0 + tn;
        if (gk < KPp) {
            u16 hi, lo; split2(tile[tn][nn], hi, lo);
            size_t o = ((size_t)l * NPp + gn) * KPp + gk;
            Thi[o] = hi; Tlo[o] = lo;
        }
    }
}

// ---------------- fused BN(prev)+ReLU reconstruct + aggregate + GIN update -> fp16 A1 ----
// AFF: hval = relu(raw*sc[t]+sh[t]) (layers>=1); else hval = raw (layer 0 atom output)
template <bool AFF>
__global__ __launch_bounds__(320) void agg_kernel(const u16* __restrict__ z2,
    const int* __restrict__ rec, const int* __restrict__ rowptr,
    const u16* __restrict__ combo_l,
    const float* __restrict__ sc, const float* __restrict__ sh,
    const float* __restrict__ eps, int l, u16* __restrict__ A1)
{
    int n = blockIdx.x;
    int t = threadIdx.x;
    if (t >= DD) {
        if (t < KP1) A1[(size_t)n * KP1 + t] = 0;
        return;
    }
    float sct = AFF ? sc[t] : 0.f;
    float sht = AFF ? sh[t] : 0.f;
    int beg = rowptr[n], end = rowptr[n + 1];
    float acc = 0.f;
    int i = beg;
    for (; i + 4 <= end; i += 4) {
        int r0 = rec[i], r1 = rec[i + 1], r2 = rec[i + 2], r3 = rec[i + 3];
        u16 a0 = z2[(size_t)(r0 & 0xFFFFF) * Z2LD + t];
        u16 a1 = z2[(size_t)(r1 & 0xFFFFF) * Z2LD + t];
        u16 a2 = z2[(size_t)(r2 & 0xFFFFF) * Z2LD + t];
        u16 a3 = z2[(size_t)(r3 & 0xFFFFF) * Z2LD + t];
        u16 b0 = combo_l[(size_t)(((unsigned)r0) >> 20) * DD + t];
        u16 b1 = combo_l[(size_t)(((unsigned)r1) >> 20) * DD + t];
        u16 b2 = combo_l[(size_t)(((unsigned)r2) >> 20) * DD + t];
        u16 b3 = combo_l[(size_t)(((unsigned)r3) >> 20) * DD + t];
        float h0 = h2f(a0), h1 = h2f(a1), h2 = h2f(a2), h3 = h2f(a3);
        if (AFF) {
            h0 = fmaxf(fmaf(h0, sct, sht), 0.f);
            h1 = fmaxf(fmaf(h1, sct, sht), 0.f);
            h2 = fmaxf(fmaf(h2, sct, sht), 0.f);
            h3 = fmaxf(fmaf(h3, sct, sht), 0.f);
        }
        acc += fmaxf(h0 + h2f(b0), 0.f) + fmaxf(h1 + h2f(b1), 0.f)
             + fmaxf(h2 + h2f(b2), 0.f) + fmaxf(h3 + h2f(b3), 0.f);
    }
    for (; i < end; ++i) {
        int r = rec[i];
        float hv = h2f(z2[(size_t)(r & 0xFFFFF) * Z2LD + t]);
        if (AFF) hv = fmaxf(fmaf(hv, sct, sht), 0.f);
        acc += fmaxf(hv + h2f(combo_l[(size_t)(((unsigned)r) >> 20) * DD + t]), 0.f);
    }
    float se = 1.0f + eps[l];
    float hn = h2f(z2[(size_t)n * Z2LD + t]);
    if (AFF) hn = fmaxf(fmaf(hn, sct, sht), 0.f);
    A1[(size_t)n * KP1 + t] = f2h(fmaf(se, hn, acc));
}

// ---------------- split-bf16 MFMA GEMM, fp16 A reg-staged, dbuf LDS, fused col-stats ----
// C[M,N] = op(A)[M,K] @ B[N,K]^T + bias; op = FUSE ? relu(A*sc[k]+sh[k]) : A
// Out fp16 [.][ldc], pad cols zeroed; col sums/sumsq atomically accumulated into cs/csq.
template <bool FUSE>
__global__ __launch_bounds__(512, 4) void gemm_rs(
    const u16* __restrict__ Af, int lda,
    const u16* __restrict__ Bhi, const u16* __restrict__ Blo,
    const float* __restrict__ bias,
    const float* __restrict__ scA, const float* __restrict__ shA,
    u16* __restrict__ O, int ldc, int M, int N, int ksteps,
    float* __restrict__ cs, float* __restrict__ csq)
{
    __shared__ __align__(16) u16 Ah[2][4][128][8];
    __shared__ __align__(16) u16 Al[2][4][128][8];
    __shared__ __align__(16) u16 Bh[2][4][128][8];
    __shared__ __align__(16) u16 Bl[2][4][128][8];
    __shared__ float sc_s[640], sh_s[640];

    const int t = threadIdx.x;
    const int lane = t & 63, w = t >> 6;
    const int l15 = lane & 15, l4 = lane >> 4;
    const int wr = w >> 2, wc = w & 3;          // wave tile: 64 rows x 32 cols
    const int col0 = blockIdx.x * 128;
    const int row0 = blockIdx.y * 128;

    if (FUSE) {
        for (int c = t; c < lda; c += 512) { sc_s[c] = scA[c]; sh_s[c] = shA[c]; }
    }

    const int arow = t >> 2;            // 0..127
    const int kg   = t & 3;             // 0..3
    const int k8   = kg * 8;
    const u16* aptr = Af + (size_t)(row0 + arow) * lda + k8;

    const int bkg = w >> 1, bch = w & 1;
    const u16* bhptr = Bhi + (size_t)(col0 + bch * 64 + lane) * lda + bkg * 8;
    const u16* blptr = Blo + (size_t)(col0 + bch * 64 + lane) * lda + bkg * 8;

    uint4 pv;
    auto loadA = [&](int ks) {
        pv = *(const uint4*)(aptr + ks * 32);
    };
    auto issueB = [&](int ks, int buf) {
        g2l16(bhptr + ks * 32, &Bh[buf][bkg][bch * 64][0]);
        g2l16(blptr + ks * 32, &Bl[buf][bkg][bch * 64][0]);
    };
    auto writeA = [&](int ks, int buf) {
        const u16* hp = (const u16*)&pv;
        u16 oh[8], ol[8];
#pragma unroll
        for (int j = 0; j < 8; ++j) {
            float xv = h2f(hp[j]);
            if (FUSE) {
                int c = ks * 32 + k8 + j;
                xv = fmaxf(fmaf(xv, sc_s[c], sh_s[c]), 0.f);
            }
            split2(xv, oh[j], ol[j]);
        }
        *(uint4*)&Ah[buf][kg][arow][0] = *(const uint4*)oh;
        *(uint4*)&Al[buf][kg][arow][0] = *(const uint4*)ol;
    };

    f32x4 acc[4][2];
#pragma unroll
    for (int i = 0; i < 4; ++i)
#pragma unroll
        for (int j = 0; j < 2; ++j) acc[i][j] = (f32x4){0.f, 0.f, 0.f, 0.f};

    __syncthreads();                    // sc_s visible
    loadA(0); issueB(0, 0); writeA(0, 0);
    __syncthreads();                    // drain g2l16 + ds_writes

    int cur = 0;
    for (int ks = 0; ks < ksteps; ++ks) {
        int nxt = cur ^ 1;
        bool more = (ks + 1 < ksteps);
        if (more) { loadA(ks + 1); issueB(ks + 1, nxt); }

        bf16x8 a_h[4], a_l[4], b_h[2], b_l[2];
#pragma unroll
        for (int i = 0; i < 4; ++i) {
            int r = wr * 64 + i * 16 + l15;
            a_h[i] = *(const bf16x8*)Ah[cur][l4][r];
            a_l[i] = *(const bf16x8*)Al[cur][l4][r];
        }
#pragma unroll
        for (int i = 0; i < 2; ++i) {
            int c = wc * 32 + i * 16 + l15;
            b_h[i] = *(const bf16x8*)Bh[cur][l4][c];
            b_l[i] = *(const bf16x8*)Bl[cur][l4][c];
        }
#pragma unroll
        for (int mi = 0; mi < 4; ++mi)
#pragma unroll
            for (int ni = 0; ni < 2; ++ni) {
                acc[mi][ni] = __builtin_amdgcn_mfma_f32_16x16x32_bf16(a_h[mi], b_h[ni], acc[mi][ni], 0, 0, 0);
                acc[mi][ni] = __builtin_amdgcn_mfma_f32_16x16x32_bf16(a_h[mi], b_l[ni], acc[mi][ni], 0, 0, 0);
                acc[mi][ni] = __builtin_amdgcn_mfma_f32_16x16x32_bf16(a_l[mi], b_h[ni], acc[mi][ni], 0, 0, 0);
            }

        if (more) writeA(ks + 1, nxt);
        __syncthreads();
        cur = nxt;
    }

    // epilogue: fp16 store + fused column stats
    float colS[2] = {0.f, 0.f}, colQ[2] = {0.f, 0.f};
#pragma unroll
    for (int ni = 0; ni < 2; ++ni) {
        int gc = col0 + wc * 32 + ni * 16 + l15;
        float bb = (gc < N) ? bias[gc] : 0.f;
#pragma unroll
        for (int mi = 0; mi < 4; ++mi)
#pragma unroll
            for (int r = 0; r < 4; ++r) {
                int gr = row0 + wr * 64 + mi * 16 + l4 * 4 + r;
                if (gr >= M) continue;
                if (gc < N) {
                    float val = acc[mi][ni][r] + bb;
                    O[(size_t)gr * ldc + gc] = f2h(val);
                    colS[ni] += val;
                    colQ[ni] += val * val;
                } else if (gc < ldc) {
                    O[(size_t)gr * ldc + gc] = 0;
                }
            }
    }
#pragma unroll
    for (int ni = 0; ni < 2; ++ni) {
        float s = colS[ni], q = colQ[ni];
        s += __shfl_xor(s, 16); s += __shfl_xor(s, 32);
        q += __shfl_xor(q, 16); q += __shfl_xor(q, 32);
        int gc = col0 + wc * 32 + ni * 16 + l15;
        if (l4 == 0 && gc < N) {
            atomicAdd(&cs[gc], s);
            atomicAdd(&csq[gc], q);
        }
    }
}

// ---------------- finalize BN; zero pad cols; self-clean stats buffers ----------------
__global__ void bn_fin(float* __restrict__ cs, float* __restrict__ csq,
                       const float* __restrict__ g, const float* __restrict__ be,
                       float* __restrict__ scale, float* __restrict__ shift,
                       int cols, int colspad, float invn)
{
    int c = blockIdx.x * blockDim.x + threadIdx.x;
    if (c >= colspad) return;
    if (c >= cols) { scale[c] = 0.f; shift[c] = 0.f; return; }
    float mu = cs[c] * invn;
    float var = csq[c] * invn - mu * mu;
    float rs = rsqrtf(var + 1e-5f);
    float sc = rs * g[c];
    scale[c] = sc;
    shift[c] = be[c] - mu * sc;
    cs[c] = 0.f;
    csq[c] = 0.f;
}

// ---------------- global_add_pool with fused BN2 (affine on sums) ----------------
__global__ __launch_bounds__(320) void pool_kernel(const u16* __restrict__ z2,
    const int* __restrict__ batch, int N,
    const float* __restrict__ sc, const float* __restrict__ sh,
    float* __restrict__ hg)
{
    int g = blockIdx.x;
    int lo = 0, hi = N;
    while (lo < hi) { int mid = (lo + hi) >> 1; if (batch[mid] < g) lo = mid + 1; else hi = mid; }
    int start = lo;
    hi = N;
    while (lo < hi) { int mid = (lo + hi) >> 1; if (batch[mid] <= g) lo = mid + 1; else hi = mid; }
    int end = lo;
    int d = threadIdx.x;
    if (d >= DD) return;
    float s = 0.f;
    for (int i = start; i < end; ++i) s += h2f(z2[(size_t)i * Z2LD + d]);
    hg[(size_t)g * DD + d] = sc[d] * s + (float)(end - start) * sh[d];
}

// ---------------- GroupNorm + head ----------------
__global__ __launch_bounds__(256) void head_kernel(const float* __restrict__ hg,
    const float* __restrict__ w, const float* __restrict__ b, float* __restrict__ out)
{
    __shared__ float red[256];
    int g = blockIdx.x, t = threadIdx.x;
    const float* row = hg + (size_t)g * DD;
    float v0 = (t < DD) ? row[t] : 0.f;
    float v1 = (t + 256 < DD) ? row[t + 256] : 0.f;

    red[t] = v0 + v1;
    __syncthreads();
    for (int o = 128; o > 0; o >>= 1) { if (t < o) red[t] += red[t + o]; __syncthreads(); }
    float mean = red[0] * (1.f / (float)DD);
    __syncthreads();

    red[t] = v0 * v0 + v1 * v1;
    __syncthreads();
    for (int o = 128; o > 0; o >>= 1) { if (t < o) red[t] += red[t + o]; __syncthreads(); }
    float var = red[0] * (1.f / (float)DD) - mean * mean;
    float rs = rsqrtf(var + 1e-5f);
    __syncthreads();

    float d0 = (t < DD) ? (v0 - mean) * rs * w[t] : 0.f;
    float d1 = (t + 256 < DD) ? (v1 - mean) * rs * w[t + 256] : 0.f;
    red[t] = d0 + d1;
    __syncthreads();
    for (int o = 128; o > 0; o >>= 1) { if (t < o) red[t] += red[t + o]; __syncthreads(); }
    if (t == 0) out[g] = red[0] + b[0];
}

extern "C" void kernel_launch(void* const* d_in, const int* in_sizes, int n_in,
                              void* d_out, int out_size, void* d_ws, size_t ws_size,
                              hipStream_t stream)
{
    (void)n_in; (void)out_size; (void)ws_size;
    const int*   x         = (const int*)  d_in[0];
    const int*   edge_idx  = (const int*)  d_in[1];
    const int*   edge_attr = (const int*)  d_in[2];
    const int*   batch     = (const int*)  d_in[3];
    const float* atom_emb  = (const float*)d_in[4];
    const float* bond_emb  = (const float*)d_in[5];
    const float* eps       = (const float*)d_in[6];
    const float* W1        = (const float*)d_in[7];
    const float* b1        = (const float*)d_in[8];
    const float* g1        = (const float*)d_in[9];
    const float* be1       = (const float*)d_in[10];
    const float* W2        = (const float*)d_in[11];
    const float* b2        = (const float*)d_in[12];
    const float* g2        = (const float*)d_in[13];
    const float* be2       = (const float*)d_in[14];
    const float* head_w    = (const float*)d_in[15];
    const float* head_b    = (const float*)d_in[16];

    const int NN = in_sizes[3];          // nodes (20000)
    const int E  = in_sizes[1] / 2;      // edges (320000)
    const int gm = (NN + 127) / 128;     // row-blocks
    const int mpad = gm * 128;

    char* p = (char*)d_ws;
    auto alloc = [&](size_t bytes) { char* r = p; p += (bytes + 255) & ~(size_t)255; return r; };

    u16* z2g    = (u16*)  alloc((size_t)NN * Z2LD * 2);     // fp16 gather source / GEMM2 out
    u16* A1     = (u16*)  alloc((size_t)mpad * KP1 * 2);    // fp16 GIN-z (GEMM1 A)
    u16* Z1     = (u16*)  alloc((size_t)mpad * KP2 * 2);    // fp16 Z1 (GEMM2 A)
    u16* W1Thi  = (u16*)  alloc((size_t)LL * NP1 * KP1 * 2);
    u16* W1Tlo  = (u16*)  alloc((size_t)LL * NP1 * KP1 * 2);
    u16* W2Thi  = (u16*)  alloc((size_t)LL * NP2 * KP2 * 2);
    u16* W2Tlo  = (u16*)  alloc((size_t)LL * NP2 * KP2 * 2);
    u16* combo  = (u16*)  alloc((size_t)LL * 512 * DD * 2);
    float* hg   = (float*)alloc((size_t)NGG * DD * 4);
    float* cs   = (float*)alloc(HH * 4 * 2);     // cs+csq contiguous
    float* csq  = cs + HH;
    float* sc1  = (float*)alloc(640 * 4);
    float* sh1  = (float*)alloc(640 * 4);
    float* sc2  = (float*)alloc(Z2LD * 4);
    float* sh2  = (float*)alloc(Z2LD * 4);
    int* cnt    = (int*)  alloc((size_t)NN * 4 * 2);   // cnt+cursor contiguous
    int* cursor = cnt + NN;
    int* rowptr = (int*)  alloc((size_t)(NN + 1) * 4);
    int* rec    = (int*)  alloc((size_t)E * 4);

    const int* src = edge_idx;
    const int* dst = edge_idx + E;

    // ---- per-call setup ----
    hipMemsetAsync(cnt, 0, (size_t)NN * 2 * sizeof(int), stream);
    hipMemsetAsync(cs, 0, (size_t)HH * 2 * sizeof(float), stream);
    csr_count<<<512, 256, 0, stream>>>(dst, E, cnt);
    scan_kernel<<<1, 1024, 0, stream>>>(cnt, rowptr, NN);
    csr_fill<<<512, 256, 0, stream>>>(src, dst, edge_attr, rowptr, cursor, rec, E);
    combo_build<<<LL * 512, 320, 0, stream>>>(bond_emb, combo);
    w_prep_t<<<LL * (KP1 / 64) * (NP1 / 64), 256, 0, stream>>>(
        W1, DD, HH, KP1, NP1, KP1 / 64, W1Thi, W1Tlo);
    w_prep_t<<<LL * ((KP2 + 63) / 64) * (NP2 / 64), 256, 0, stream>>>(
        W2, HH, DD, KP2, NP2, (KP2 + 63) / 64, W2Thi, W2Tlo);
    atom_kernel<<<NN, 320, 0, stream>>>(x, atom_emb, z2g, NN);

    for (int l = 0; l < LL; ++l) {
        const u16* combo_l = combo + (size_t)l * 512 * DD;
        if (l == 0)
            agg_kernel<false><<<NN, 320, 0, stream>>>(z2g, rec, rowptr, combo_l,
                nullptr, nullptr, eps, l, A1);
        else
            agg_kernel<true><<<NN, 320, 0, stream>>>(z2g, rec, rowptr, combo_l,
                sc2, sh2, eps, l, A1);

        gemm_rs<false><<<dim3(NP1 / 128, gm), 512, 0, stream>>>(
            A1, KP1,
            W1Thi + (size_t)l * NP1 * KP1, W1Tlo + (size_t)l * NP1 * KP1,
            b1 + (size_t)l * HH, nullptr, nullptr,
            Z1, KP2, NN, HH, KP1 / 32, cs, csq);

        bn_fin<<<(KP2 + 255) / 256, 256, 0, stream>>>(cs, csq, g1 + (size_t)l * HH,
            be1 + (size_t)l * HH, sc1, sh1, HH, KP2, 1.f / (float)NN);

        gemm_rs<true><<<dim3(NP2 / 128, gm), 512, 0, stream>>>(
            Z1, KP2,
            W2Thi + (size_t)l * NP2 * KP2, W2Tlo + (size_t)l * NP2 * KP2,
            b2 + (size_t)l * DD, sc1, sh1,
            z2g, Z2LD, NN, DD, KP2 / 32, cs, csq);

        bn_fin<<<(Z2LD + 255) / 256, 256, 0, stream>>>(cs, csq, g2 + (size_t)l * DD,
            be2 + (size_t)l * DD, sc2, sh2, DD, Z2LD, 1.f / (float)NN);
    }

    pool_kernel<<<NGG, 320, 0, stream>>>(z2g, batch, NN, sc2, sh2, hg);
    head_kernel<<<NGG, 256, 0, stream>>>(hg, head_w, head_b, (float*)d_out);
}

// Round 7
// 890.906 us; speedup vs baseline: 4.3757x; 1.1057x over previous
//
#include <hip/hip_runtime.h>
#include <cstddef>
#include <cstdint>

#define DD 300
#define HH 600
#define LL 5
#define NGG 512
#define KP1 320     // padded K for GEMM1 (fp16 A row stride)
#define KP2 608     // padded K for GEMM2 (fp16 Z1 row stride)
#define NP1 640     // padded N of W1^T (600 -> 5 col-blocks of 128)
#define NP2 384     // padded N of W2^T (300 -> 3 col-blocks of 128)
#define Z2LD 304    // fp16 z2/h row stride
#define CLD 304     // fp16 combo row stride (16B-aligned rows)

typedef unsigned short u16;
typedef _Float16 f16x8 __attribute__((ext_vector_type(8)));
typedef float f32x4 __attribute__((ext_vector_type(4)));

__device__ __forceinline__ u16 f2h(float v)
{
    _Float16 h = (_Float16)v; u16 u; __builtin_memcpy(&u, &h, 2); return u;
}
__device__ __forceinline__ float h2f(u16 u)
{
    _Float16 h; __builtin_memcpy(&h, &u, 2); return (float)h;
}

__device__ __forceinline__ void g2l16(const void* g, void* l)
{
    __builtin_amdgcn_global_load_lds(
        (const __attribute__((address_space(1))) void*)g,
        (__attribute__((address_space(3))) void*)l, 16, 0, 0);
}

// ---------------- Atom encoder -> fp16 z2 (layer-0 gather source) ----------------
__global__ __launch_bounds__(320) void atom_kernel(const int* __restrict__ x,
    const float* __restrict__ emb, u16* __restrict__ z2, int N)
{
    __shared__ int xi[9];
    int n = blockIdx.x;
    int t = threadIdx.x;
    if (t < 9) xi[t] = x[n * 9 + t] + t * 64;
    __syncthreads();
    if (t >= Z2LD) return;
    if (t >= DD) { z2[(size_t)n * Z2LD + t] = 0; return; }
    float s = 0.f;
#pragma unroll
    for (int f = 0; f < 9; ++f) s += emb[(size_t)xi[f] * DD + t];
    z2[(size_t)n * Z2LD + t] = f2h(s);
}

// ---------------- CSR build ----------------
__global__ void csr_count(const int* __restrict__ dst, int E, int* __restrict__ cnt)
{
    int i = blockIdx.x * blockDim.x + threadIdx.x;
    int stride = gridDim.x * blockDim.x;
    for (; i < E; i += stride) atomicAdd(&cnt[dst[i]], 1);
}

__global__ __launch_bounds__(1024) void scan_kernel(const int* __restrict__ cnt,
    int* __restrict__ rowptr, int n)
{
    __shared__ int buf[1024];
    int t = threadIdx.x;
    int carry = 0;
    for (int base = 0; base < n; base += 1024) {
        int v = (base + t < n) ? cnt[base + t] : 0;
        buf[t] = v;
        __syncthreads();
        for (int off = 1; off < 1024; off <<= 1) {
            int x = (t >= off) ? buf[t - off] : 0;
            __syncthreads();
            buf[t] += x;
            __syncthreads();
        }
        if (base + t < n) rowptr[base + t] = buf[t] - v + carry;
        int total = buf[1023];
        __syncthreads();
        carry += total;
    }
    if (t == 0) rowptr[n] = carry;
}

__global__ void csr_fill(const int* __restrict__ src, const int* __restrict__ dst,
    const int* __restrict__ ea, const int* __restrict__ rowptr,
    int* __restrict__ cursor, int* __restrict__ rec, int E)
{
    int i = blockIdx.x * blockDim.x + threadIdx.x;
    int stride = gridDim.x * blockDim.x;
    for (; i < E; i += stride) {
        int d = dst[i];
        int pos = rowptr[d] + atomicAdd(&cursor[d], 1);
        int code = ea[i * 3] | (ea[i * 3 + 1] << 3) | (ea[i * 3 + 2] << 6);
        rec[pos] = src[i] | (code << 20);
    }
}

// ---------------- per-layer bond-code combo table (fp16, stride 304) ----------------
__global__ __launch_bounds__(320) void combo_build(const float* __restrict__ bond,
    u16* __restrict__ combo)
{
    int blk = blockIdx.x;           // l*512 + code
    int l = blk >> 9, code = blk & 511;
    int t = threadIdx.x;
    if (t >= CLD) return;
    u16 val = 0;
    if (t < DD) {
        const float* bl = bond + (size_t)l * 24 * DD;
        float v = bl[(size_t)(code & 7) * DD + t]
                + bl[(size_t)(8 + ((code >> 3) & 7)) * DD + t]
                + bl[(size_t)(16 + (code >> 6)) * DD + t];
        val = f2h(v);
    }
    combo[(size_t)blk * CLD + t] = val;
}

// ---------------- LDS-tiled weight transpose + f16 hi / scaled-lo split ----------------
// W [L][K][N] fp32 -> T [L][NPp][KPp]: Thi = f16(w), Tlo = f16((w - Thi) * 2048)
__global__ __launch_bounds__(256) void w_prep_t(const float* __restrict__ W,
    int K, int N, int KPp, int NPp, int ktiles,
    u16* __restrict__ Thi, u16* __restrict__ Tlo)
{
    __shared__ float tile[64][65];
    int ntiles = NPp >> 6;
    int blk = blockIdx.x;
    int l = blk / (ktiles * ntiles);
    int rem = blk % (ktiles * ntiles);
    int k0 = (rem / ntiles) << 6;
    int n0 = (rem % ntiles) << 6;
    int tn = threadIdx.x & 63;
    int tg = threadIdx.x >> 6;
    const float* Wl = W + (size_t)l * K * N;
    for (int kk = tg; kk < 64; kk += 4) {
        int gk = k0 + kk, gn = n0 + tn;
        tile[kk][tn] = (gk < K && gn < N) ? Wl[(size_t)gk * N + gn] : 0.f;
    }
    __syncthreads();
    for (int nn = tg; nn < 64; nn += 4) {
        int gn = n0 + nn, gk = k0 + tn;
        if (gk < KPp) {
            float v = tile[tn][nn];
            u16 hi = f2h(v);
            u16 lo = f2h((v - h2f(hi)) * 2048.0f);
            size_t o = ((size_t)l * NPp + gn) * KPp + gk;
            Thi[o] = hi; Tlo[o] = lo;
        }
    }
}

// ---------------- fused BN(prev)+ReLU + aggregate + GIN update -> fp16 A1 ----------------
// 256 threads = 4 waves; each wave: 38 lanes x ushort8 cover 304 dims, waves stride edges.
template <bool AFF>
__global__ __launch_bounds__(256) void agg_kernel(const u16* __restrict__ z2,
    const int* __restrict__ rec, const int* __restrict__ rowptr,
    const u16* __restrict__ combo_l,
    const float* __restrict__ sc, const float* __restrict__ sh,
    const float* __restrict__ eps, int l, u16* __restrict__ A1)
{
    __shared__ float part[4][304];
    int n = blockIdx.x;
    int t = threadIdx.x;
    int w = t >> 6, lane = t & 63;
    int d0 = lane * 8;
    int beg = rowptr[n], end = rowptr[n + 1];

    if (d0 < 304) {
        float acc[8] = {0.f, 0.f, 0.f, 0.f, 0.f, 0.f, 0.f, 0.f};
        float scv[8], shv[8];
        if (AFF) {
#pragma unroll
            for (int j = 0; j < 8; ++j) { scv[j] = sc[d0 + j]; shv[j] = sh[d0 + j]; }
        }
        int i = beg + w;
        for (; i + 4 < end; i += 8) {          // unroll 2 (wave stride 4)
            int r0 = rec[i], r1 = rec[i + 4];
            uint4 hv0 = *(const uint4*)(z2 + (size_t)(r0 & 0xFFFFF) * Z2LD + d0);
            uint4 cv0 = *(const uint4*)(combo_l + (size_t)(((unsigned)r0) >> 20) * CLD + d0);
            uint4 hv1 = *(const uint4*)(z2 + (size_t)(r1 & 0xFFFFF) * Z2LD + d0);
            uint4 cv1 = *(const uint4*)(combo_l + (size_t)(((unsigned)r1) >> 20) * CLD + d0);
            const u16* hp0 = (const u16*)&hv0; const u16* cp0 = (const u16*)&cv0;
            const u16* hp1 = (const u16*)&hv1; const u16* cp1 = (const u16*)&cv1;
#pragma unroll
            for (int j = 0; j < 8; ++j) {
                float h0 = h2f(hp0[j]), h1 = h2f(hp1[j]);
                if (AFF) {
                    h0 = fmaxf(fmaf(h0, scv[j], shv[j]), 0.f);
                    h1 = fmaxf(fmaf(h1, scv[j], shv[j]), 0.f);
                }
                acc[j] += fmaxf(h0 + h2f(cp0[j]), 0.f) + fmaxf(h1 + h2f(cp1[j]), 0.f);
            }
        }
        for (; i < end; i += 4) {
            int r0 = rec[i];
            uint4 hv0 = *(const uint4*)(z2 + (size_t)(r0 & 0xFFFFF) * Z2LD + d0);
            uint4 cv0 = *(const uint4*)(combo_l + (size_t)(((unsigned)r0) >> 20) * CLD + d0);
            const u16* hp0 = (const u16*)&hv0; const u16* cp0 = (const u16*)&cv0;
#pragma unroll
            for (int j = 0; j < 8; ++j) {
                float h0 = h2f(hp0[j]);
                if (AFF) h0 = fmaxf(fmaf(h0, scv[j], shv[j]), 0.f);
                acc[j] += fmaxf(h0 + h2f(cp0[j]), 0.f);
            }
        }
        *(float4*)&part[w][d0]     = *(const float4*)&acc[0];
        *(float4*)&part[w][d0 + 4] = *(const float4*)&acc[4];
    }
    __syncthreads();

    if (t < 152) {
        float se = 1.0f + eps[l];
        int d = t * 2;
#pragma unroll
        for (int k = 0; k < 2; ++k) {
            int dd = d + k;
            float s = part[0][dd] + part[1][dd] + part[2][dd] + part[3][dd];
            float hn = h2f(z2[(size_t)n * Z2LD + dd]);
            if (AFF) hn = fmaxf(fmaf(hn, sc[dd], sh[dd]), 0.f);
            A1[(size_t)n * KP1 + dd] = f2h(fmaf(se, hn, s));
        }
    } else if (t < 160) {
        int d = 304 + (t - 152) * 2;
        A1[(size_t)n * KP1 + d] = 0;
        A1[(size_t)n * KP1 + d + 1] = 0;
    }
}

// ---------------- f16 MFMA GEMM (2-pass W split), reg-staged fp16 A, dbuf LDS ----------
// C[M,N] = op(A)[M,K] @ (Whi + Wlo/2048)[N,K]^T + bias; op = FUSE ? relu(A*sc+sh) : A
// Out fp16 [.][ldc], pad cols zeroed; col sums/sumsq accumulated into cs/csq.
template <bool FUSE>
__global__ __launch_bounds__(512, 4) void gemm_rs(
    const u16* __restrict__ Af, int lda,
    const u16* __restrict__ Bhi, const u16* __restrict__ Blo,
    const float* __restrict__ bias,
    const float* __restrict__ scA, const float* __restrict__ shA,
    u16* __restrict__ O, int ldc, int M, int N, int ksteps,
    float* __restrict__ cs, float* __restrict__ csq)
{
    __shared__ __align__(16) u16 As[2][4][128][8];
    __shared__ __align__(16) u16 Bh[2][4][128][8];
    __shared__ __align__(16) u16 Bl[2][4][128][8];
    __shared__ float sc_s[640], sh_s[640];

    const int t = threadIdx.x;
    const int lane = t & 63, w = t >> 6;
    const int l15 = lane & 15, l4 = lane >> 4;
    const int wr = w >> 2, wc = w & 3;          // wave tile: 64 rows x 32 cols
    const int col0 = blockIdx.x * 128;
    const int row0 = blockIdx.y * 128;

    if (FUSE) {
        for (int c = t; c < lda; c += 512) { sc_s[c] = scA[c]; sh_s[c] = shA[c]; }
    }

    const int arow = t >> 2;            // 0..127
    const int kg   = t & 3;             // 0..3
    const int k8   = kg * 8;
    const u16* aptr = Af + (size_t)(row0 + arow) * lda + k8;

    const int bkg = w >> 1, bch = w & 1;
    const u16* bhptr = Bhi + (size_t)(col0 + bch * 64 + lane) * lda + bkg * 8;
    const u16* blptr = Blo + (size_t)(col0 + bch * 64 + lane) * lda + bkg * 8;

    uint4 pv;
    auto loadA = [&](int ks) {
        pv = *(const uint4*)(aptr + ks * 32);
    };
    auto issueB = [&](int ks, int buf) {
        g2l16(bhptr + ks * 32, &Bh[buf][bkg][bch * 64][0]);
        g2l16(blptr + ks * 32, &Bl[buf][bkg][bch * 64][0]);
    };
    auto writeA = [&](int ks, int buf) {
        if (FUSE) {
            const u16* hp = (const u16*)&pv;
            u16 oh[8];
#pragma unroll
            for (int j = 0; j < 8; ++j) {
                int c = ks * 32 + k8 + j;
                float xv = fmaxf(fmaf(h2f(hp[j]), sc_s[c], sh_s[c]), 0.f);
                oh[j] = f2h(xv);
            }
            *(uint4*)&As[buf][kg][arow][0] = *(const uint4*)oh;
        } else {
            *(uint4*)&As[buf][kg][arow][0] = pv;
        }
    };

    f32x4 acc[4][2], acc2[4][2];
#pragma unroll
    for (int i = 0; i < 4; ++i)
#pragma unroll
        for (int j = 0; j < 2; ++j) {
            acc[i][j] = (f32x4){0.f, 0.f, 0.f, 0.f};
            acc2[i][j] = (f32x4){0.f, 0.f, 0.f, 0.f};
        }

    __syncthreads();                    // sc_s visible
    loadA(0); issueB(0, 0); writeA(0, 0);
    __syncthreads();                    // drain g2l16 + ds_writes

    int cur = 0;
    for (int ks = 0; ks < ksteps; ++ks) {
        int nxt = cur ^ 1;
        bool more = (ks + 1 < ksteps);
        if (more) { loadA(ks + 1); issueB(ks + 1, nxt); }

        f16x8 a[4], b_h[2], b_l[2];
#pragma unroll
        for (int i = 0; i < 4; ++i) {
            int r = wr * 64 + i * 16 + l15;
            a[i] = *(const f16x8*)As[cur][l4][r];
        }
#pragma unroll
        for (int i = 0; i < 2; ++i) {
            int c = wc * 32 + i * 16 + l15;
            b_h[i] = *(const f16x8*)Bh[cur][l4][c];
            b_l[i] = *(const f16x8*)Bl[cur][l4][c];
        }
#pragma unroll
        for (int mi = 0; mi < 4; ++mi)
#pragma unroll
            for (int ni = 0; ni < 2; ++ni) {
                acc[mi][ni]  = __builtin_amdgcn_mfma_f32_16x16x32_f16(a[mi], b_h[ni], acc[mi][ni], 0, 0, 0);
                acc2[mi][ni] = __builtin_amdgcn_mfma_f32_16x16x32_f16(a[mi], b_l[ni], acc2[mi][ni], 0, 0, 0);
            }

        if (more) writeA(ks + 1, nxt);
        __syncthreads();
        cur = nxt;
    }

    // epilogue: recombine (acc + acc2/2048) + bias, fp16 store + fused column stats
    float colS[2] = {0.f, 0.f}, colQ[2] = {0.f, 0.f};
#pragma unroll
    for (int ni = 0; ni < 2; ++ni) {
        int gc = col0 + wc * 32 + ni * 16 + l15;
        float bb = (gc < N) ? bias[gc] : 0.f;
#pragma unroll
        for (int mi = 0; mi < 4; ++mi)
#pragma unroll
            for (int r = 0; r < 4; ++r) {
                int gr = row0 + wr * 64 + mi * 16 + l4 * 4 + r;
                if (gr >= M) continue;
                if (gc < N) {
                    float val = fmaf(acc2[mi][ni][r], 4.8828125e-4f, acc[mi][ni][r]) + bb;
                    O[(size_t)gr * ldc + gc] = f2h(val);
                    colS[ni] += val;
                    colQ[ni] += val * val;
                } else if (gc < ldc) {
                    O[(size_t)gr * ldc + gc] = 0;
                }
            }
    }
#pragma unroll
    for (int ni = 0; ni < 2; ++ni) {
        float s = colS[ni], q = colQ[ni];
        s += __shfl_xor(s, 16); s += __shfl_xor(s, 32);
        q += __shfl_xor(q, 16); q += __shfl_xor(q, 32);
        int gc = col0 + wc * 32 + ni * 16 + l15;
        if (l4 == 0 && gc < N) {
            atomicAdd(&cs[gc], s);
            atomicAdd(&csq[gc], q);
        }
    }
}

// ---------------- finalize BN; zero pad cols; self-clean stats buffers ----------------
__global__ void bn_fin(float* __restrict__ cs, float* __restrict__ csq,
                       const float* __restrict__ g, const float* __restrict__ be,
                       float* __restrict__ scale, float* __restrict__ shift,
                       int cols, int colspad, float invn)
{
    int c = blockIdx.x * blockDim.x + threadIdx.x;
    if (c >= colspad) return;
    if (c >= cols) { scale[c] = 0.f; shift[c] = 0.f; return; }
    float mu = cs[c] * invn;
    float var = csq[c] * invn - mu * mu;
    float rs = rsqrtf(var + 1e-5f);
    float sc = rs * g[c];
    scale[c] = sc;
    shift[c] = be[c] - mu * sc;
    cs[c] = 0.f;
    csq[c] = 0.f;
}

// ---------------- global_add_pool with fused BN2 (affine on sums) ----------------
__global__ __launch_bounds__(320) void pool_kernel(const u16* __restrict__ z2,
    const int* __restrict__ batch, int N,
    const float* __restrict__ sc, const float* __restrict__ sh,
    float* __restrict__ hg)
{
    int g = blockIdx.x;
    int lo = 0, hi = N;
    while (lo < hi) { int mid = (lo + hi) >> 1; if (batch[mid] < g) lo = mid + 1; else hi = mid; }
    int start = lo;
    hi = N;
    while (lo < hi) { int mid = (lo + hi) >> 1; if (batch[mid] <= g) lo = mid + 1; else hi = mid; }
    int end = lo;
    int d = threadIdx.x;
    if (d >= DD) return;
    float s = 0.f;
    for (int i = start; i < end; ++i) s += h2f(z2[(size_t)i * Z2LD + d]);
    hg[(size_t)g * DD + d] = sc[d] * s + (float)(end - start) * sh[d];
}

// ---------------- GroupNorm + head ----------------
__global__ __launch_bounds__(256) void head_kernel(const float* __restrict__ hg,
    const float* __restrict__ w, const float* __restrict__ b, float* __restrict__ out)
{
    __shared__ float red[256];
    int g = blockIdx.x, t = threadIdx.x;
    const float* row = hg + (size_t)g * DD;
    float v0 = (t < DD) ? row[t] : 0.f;
    float v1 = (t + 256 < DD) ? row[t + 256] : 0.f;

    red[t] = v0 + v1;
    __syncthreads();
    for (int o = 128; o > 0; o >>= 1) { if (t < o) red[t] += red[t + o]; __syncthreads(); }
    float mean = red[0] * (1.f / (float)DD);
    __syncthreads();

    red[t] = v0 * v0 + v1 * v1;
    __syncthreads();
    for (int o = 128; o > 0; o >>= 1) { if (t < o) red[t] += red[t + o]; __syncthreads(); }
    float var = red[0] * (1.f / (float)DD) - mean * mean;
    float rs = rsqrtf(var + 1e-5f);
    __syncthreads();

    float d0 = (t < DD) ? (v0 - mean) * rs * w[t] : 0.f;
    float d1 = (t + 256 < DD) ? (v1 - mean) * rs * w[t + 256] : 0.f;
    red[t] = d0 + d1;
    __syncthreads();
    for (int o = 128; o > 0; o >>= 1) { if (t < o) red[t] += red[t + o]; __syncthreads(); }
    if (t == 0) out[g] = red[0] + b[0];
}

extern "C" void kernel_launch(void* const* d_in, const int* in_sizes, int n_in,
                              void* d_out, int out_size, void* d_ws, size_t ws_size,
                              hipStream_t stream)
{
    (void)n_in; (void)out_size; (void)ws_size;
    const int*   x         = (const int*)  d_in[0];
    const int*   edge_idx  = (const int*)  d_in[1];
    const int*   edge_attr = (const int*)  d_in[2];
    const int*   batch     = (const int*)  d_in[3];
    const float* atom_emb  = (const float*)d_in[4];
    const float* bond_emb  = (const float*)d_in[5];
    const float* eps       = (const float*)d_in[6];
    const float* W1        = (const float*)d_in[7];
    const float* b1        = (const float*)d_in[8];
    const float* g1        = (const float*)d_in[9];
    const float* be1       = (const float*)d_in[10];
    const float* W2        = (const float*)d_in[11];
    const float* b2        = (const float*)d_in[12];
    const float* g2        = (const float*)d_in[13];
    const float* be2       = (const float*)d_in[14];
    const float* head_w    = (const float*)d_in[15];
    const float* head_b    = (const float*)d_in[16];

    const int NN = in_sizes[3];          // nodes (20000)
    const int E  = in_sizes[1] / 2;      // edges (320000)
    const int gm = (NN + 127) / 128;     // row-blocks
    const int mpad = gm * 128;

    char* p = (char*)d_ws;
    auto alloc = [&](size_t bytes) { char* r = p; p += (bytes + 255) & ~(size_t)255; return r; };

    u16* z2g    = (u16*)  alloc((size_t)NN * Z2LD * 2);     // fp16 gather source / GEMM2 out
    u16* A1     = (u16*)  alloc((size_t)mpad * KP1 * 2);    // fp16 GIN-z (GEMM1 A)
    u16* Z1     = (u16*)  alloc((size_t)mpad * KP2 * 2);    // fp16 Z1 (GEMM2 A)
    u16* W1Thi  = (u16*)  alloc((size_t)LL * NP1 * KP1 * 2);
    u16* W1Tlo  = (u16*)  alloc((size_t)LL * NP1 * KP1 * 2);
    u16* W2Thi  = (u16*)  alloc((size_t)LL * NP2 * KP2 * 2);
    u16* W2Tlo  = (u16*)  alloc((size_t)LL * NP2 * KP2 * 2);
    u16* combo  = (u16*)  alloc((size_t)LL * 512 * CLD * 2);
    float* hg   = (float*)alloc((size_t)NGG * DD * 4);
    float* cs   = (float*)alloc(HH * 4 * 2);     // cs+csq contiguous
    float* csq  = cs + HH;
    float* sc1  = (float*)alloc(640 * 4);
    float* sh1  = (float*)alloc(640 * 4);
    float* sc2  = (float*)alloc(Z2LD * 4);
    float* sh2  = (float*)alloc(Z2LD * 4);
    int* cnt    = (int*)  alloc((size_t)NN * 4 * 2);   // cnt+cursor contiguous
    int* cursor = cnt + NN;
    int* rowptr = (int*)  alloc((size_t)(NN + 1) * 4);
    int* rec    = (int*)  alloc((size_t)E * 4);

    const int* src = edge_idx;
    const int* dst = edge_idx + E;

    // ---- per-call setup ----
    hipMemsetAsync(cnt, 0, (size_t)NN * 2 * sizeof(int), stream);
    hipMemsetAsync(cs, 0, (size_t)HH * 2 * sizeof(float), stream);
    csr_count<<<512, 256, 0, stream>>>(dst, E, cnt);
    scan_kernel<<<1, 1024, 0, stream>>>(cnt, rowptr, NN);
    csr_fill<<<512, 256, 0, stream>>>(src, dst, edge_attr, rowptr, cursor, rec, E);
    combo_build<<<LL * 512, 320, 0, stream>>>(bond_emb, combo);
    w_prep_t<<<LL * (KP1 / 64) * (NP1 / 64), 256, 0, stream>>>(
        W1, DD, HH, KP1, NP1, KP1 / 64, W1Thi, W1Tlo);
    w_prep_t<<<LL * ((KP2 + 63) / 64) * (NP2 / 64), 256, 0, stream>>>(
        W2, HH, DD, KP2, NP2, (KP2 + 63) / 64, W2Thi, W2Tlo);
    atom_kernel<<<NN, 320, 0, stream>>>(x, atom_emb, z2g, NN);

    for (int l = 0; l < LL; ++l) {
        const u16* combo_l = combo + (size_t)l * 512 * CLD;
        if (l == 0)
            agg_kernel<false><<<NN, 256, 0, stream>>>(z2g, rec, rowptr, combo_l,
                nullptr, nullptr, eps, l, A1);
        else
            agg_kernel<true><<<NN, 256, 0, stream>>>(z2g, rec, rowptr, combo_l,
                sc2, sh2, eps, l, A1);

        gemm_rs<false><<<dim3(NP1 / 128, gm), 512, 0, stream>>>(
            A1, KP1,
            W1Thi + (size_t)l * NP1 * KP1, W1Tlo + (size_t)l * NP1 * KP1,
            b1 + (size_t)l * HH, nullptr, nullptr,
            Z1, KP2, NN, HH, KP1 / 32, cs, csq);

        bn_fin<<<(KP2 + 255) / 256, 256, 0, stream>>>(cs, csq, g1 + (size_t)l * HH,
            be1 + (size_t)l * HH, sc1, sh1, HH, KP2, 1.f / (float)NN);

        gemm_rs<true><<<dim3(NP2 / 128, gm), 512, 0, stream>>>(
            Z1, KP2,
            W2Thi + (size_t)l * NP2 * KP2, W2Tlo + (size_t)l * NP2 * KP2,
            b2 + (size_t)l * DD, sc1, sh1,
            z2g, Z2LD, NN, DD, KP2 / 32, cs, csq);

        bn_fin<<<(Z2LD + 255) / 256, 256, 0, stream>>>(cs, csq, g2 + (size_t)l * DD,
            be2 + (size_t)l * DD, sc2, sh2, DD, Z2LD, 1.f / (float)NN);
    }

    pool_kernel<<<NGG, 320, 0, stream>>>(z2g, batch, NN, sc2, sh2, hg);
    head_kernel<<<NGG, 256, 0, stream>>>(hg, head_w, head_b, (float*)d_out);
}